// Round 1
// baseline (2642.976 us; speedup 1.0000x reference)
//
#include <hip/hip_runtime.h>
#include <math.h>

constexpr float F_CUTOFF = 10.0f;
constexpr float F_EPS_W  = 1e-5f;
constexpr float F_EPS_LN = 1e-5f;
constexpr float F_PI     = 3.14159265358979323846f;

__device__ __forceinline__ float silu_f(float v)   { return v / (1.0f + __expf(-v)); }
__device__ __forceinline__ float sigmoid_f(float v){ return 1.0f / (1.0f + __expf(-v)); }

__device__ __forceinline__ float f4c(const float4& v, int q) {
    return q == 0 ? v.x : q == 1 ? v.y : q == 2 ? v.z : v.w;
}

// ---------------------------------------------------------------------------
// Generic [M,256] x [256,256] GEMM, 64-row tile, 8x8 micro-tile per thread.
// MODE 0: out = A@W + b
// MODE 1: out = A * sigmoid(A@W + b)   (elementwise A, for the gate)
// ---------------------------------------------------------------------------
template<int MODE>
__global__ __launch_bounds__(256)
void gemm256_kernel(const float* __restrict__ A, const float* __restrict__ Wm,
                    const float* __restrict__ bias, float* __restrict__ out, int M)
{
    __shared__ float4 As4[64][64];   // 64 rows x 256 cols (as float4)
    const int t = threadIdx.x;
    const int row0 = blockIdx.x * 64;

    #pragma unroll
    for (int i = 0; i < 16; ++i) {
        int flat = t + i * 256;          // float4 index within tile
        int r = flat >> 6, k4 = flat & 63;
        int row = row0 + r;
        float4 v = make_float4(0.f, 0.f, 0.f, 0.f);
        if (row < M) v = reinterpret_cast<const float4*>(A)[row * 64 + k4];
        As4[r][k4] = v;
    }
    __syncthreads();

    const int jt  = t & 31;
    const int et  = t >> 5;
    const int j04 = jt * 2;      // float4 col index; j0 = jt*8
    const int r0  = et * 8;

    float acc[8][8];
    #pragma unroll
    for (int r = 0; r < 8; ++r)
        #pragma unroll
        for (int c = 0; c < 8; ++c) acc[r][c] = 0.f;

    for (int k4 = 0; k4 < 64; ++k4) {
        float4 a4[8];
        #pragma unroll
        for (int r = 0; r < 8; ++r) a4[r] = As4[r0 + r][k4];   // wave-broadcast reads
        #pragma unroll
        for (int q = 0; q < 4; ++q) {
            const int k = k4 * 4 + q;
            float4 b0 = reinterpret_cast<const float4*>(Wm)[k * 64 + j04];
            float4 b1 = reinterpret_cast<const float4*>(Wm)[k * 64 + j04 + 1];
            float bb[8] = {b0.x, b0.y, b0.z, b0.w, b1.x, b1.y, b1.z, b1.w};
            #pragma unroll
            for (int r = 0; r < 8; ++r) {
                float av = f4c(a4[r], q);
                #pragma unroll
                for (int c = 0; c < 8; ++c) acc[r][c] = fmaf(av, bb[c], acc[r][c]);
            }
        }
    }

    float4 bv0 = reinterpret_cast<const float4*>(bias)[j04];
    float4 bv1 = reinterpret_cast<const float4*>(bias)[j04 + 1];
    float bb[8] = {bv0.x, bv0.y, bv0.z, bv0.w, bv1.x, bv1.y, bv1.z, bv1.w};

    #pragma unroll
    for (int r = 0; r < 8; ++r) {
        int row = row0 + r0 + r;
        if (row >= M) continue;
        float o[8];
        #pragma unroll
        for (int c = 0; c < 8; ++c) o[c] = acc[r][c] + bb[c];
        if (MODE == 1) {
            float4 a0 = As4[r0 + r][j04];
            float4 a1 = As4[r0 + r][j04 + 1];
            float aa[8] = {a0.x, a0.y, a0.z, a0.w, a1.x, a1.y, a1.z, a1.w};
            #pragma unroll
            for (int c = 0; c < 8; ++c) o[c] = aa[c] * sigmoid_f(o[c]);
        }
        reinterpret_cast<float4*>(out)[row * 64 + j04]     = make_float4(o[0], o[1], o[2], o[3]);
        reinterpret_cast<float4*>(out)[row * 64 + j04 + 1] = make_float4(o[4], o[5], o[6], o[7]);
    }
}

// ---------------------------------------------------------------------------
// Fused per-edge pipeline: RBF -> rbf MLP (64->64->64) -> filter net
// (64->256->256->256) -> modulate gathered y[col] -> atomic scatter into agg.
// 32 edges per block, 256 threads.
// ---------------------------------------------------------------------------
__global__ __launch_bounds__(256)
void edge_kernel(const float* __restrict__ dist, const int* __restrict__ eidx,
                 const float* __restrict__ centers, const float* __restrict__ widths,
                 const float* __restrict__ rbf_w1, const float* __restrict__ rbf_b1,
                 const float* __restrict__ rbf_w2, const float* __restrict__ rbf_b2,
                 const float* __restrict__ filt_w1, const float* __restrict__ filt_b1,
                 const float* __restrict__ filt_w2, const float* __restrict__ filt_b2,
                 const float* __restrict__ filt_w3, const float* __restrict__ filt_b3,
                 const float* __restrict__ y, float* __restrict__ agg, int E)
{
    __shared__ float f1_s[32 * 256];   // 32 KB
    __shared__ float f2_s[32 * 256];   // 32 KB; start of life: r / t1 / t2 buffers
    __shared__ float d_s[32], env_s[32];
    __shared__ int   row_s[32], col_s[32];

    float* r_s  = f2_s;          // [32][64]
    float* t1_s = f2_s + 2048;   // [32][64]
    float* t2_s = f2_s + 4096;   // [32][64]

    const int t  = threadIdx.x;
    const int e0 = blockIdx.x * 32;

    if (t < 32) {
        int ge = e0 + t;
        float d = (ge < E) ? dist[ge] : F_CUTOFF;
        d_s[t] = d;
        env_s[t] = (d < F_CUTOFF) ? 0.5f * (__cosf(d * (F_PI / F_CUTOFF)) + 1.0f) : 0.0f;
        row_s[t] = (ge < E) ? eidx[ge] : 0;
        col_s[t] = (ge < E) ? eidx[E + ge] : 0;
    }
    __syncthreads();

    // ---- stage 0: r = env * gaussian(d; centers, widths)   [32][64]
    #pragma unroll
    for (int i = 0; i < 8; ++i) {
        int idx = t + i * 256;
        int e = idx >> 6, k = idx & 63;
        float d = d_s[e];
        float w = fabsf(widths[k]) + F_EPS_W;
        float z = (d - centers[k]) / w;
        r_s[idx] = env_s[e] * __expf(-0.5f * z * z);
    }
    __syncthreads();

    // ---- stages 1,2: t1 = silu(r@rbf_w1+b1); t2 = t1@rbf_w2+b2   (M=32,N=64,K=64)
    {
        const int j  = t & 63;
        const int eg = (t >> 6) * 8;   // 8 edges per thread
        float acc1[8];
        #pragma unroll
        for (int r = 0; r < 8; ++r) acc1[r] = 0.f;
        for (int k4 = 0; k4 < 16; ++k4) {
            float4 a4[8];
            #pragma unroll
            for (int r = 0; r < 8; ++r)
                a4[r] = reinterpret_cast<float4*>(r_s)[(eg + r) * 16 + k4];
            #pragma unroll
            for (int q = 0; q < 4; ++q) {
                float b = rbf_w1[(k4 * 4 + q) * 64 + j];
                #pragma unroll
                for (int r = 0; r < 8; ++r) acc1[r] = fmaf(f4c(a4[r], q), b, acc1[r]);
            }
        }
        float bias1 = rbf_b1[j];
        #pragma unroll
        for (int r = 0; r < 8; ++r) t1_s[(eg + r) * 64 + j] = silu_f(acc1[r] + bias1);
        __syncthreads();

        float acc2[8];
        #pragma unroll
        for (int r = 0; r < 8; ++r) acc2[r] = 0.f;
        for (int k4 = 0; k4 < 16; ++k4) {
            float4 a4[8];
            #pragma unroll
            for (int r = 0; r < 8; ++r)
                a4[r] = reinterpret_cast<float4*>(t1_s)[(eg + r) * 16 + k4];
            #pragma unroll
            for (int q = 0; q < 4; ++q) {
                float b = rbf_w2[(k4 * 4 + q) * 64 + j];
                #pragma unroll
                for (int r = 0; r < 8; ++r) acc2[r] = fmaf(f4c(a4[r], q), b, acc2[r]);
            }
        }
        float bias2 = rbf_b2[j];
        #pragma unroll
        for (int r = 0; r < 8; ++r) t2_s[(eg + r) * 64 + j] = acc2[r] + bias2;  // no silu
        __syncthreads();
    }

    const int jt  = t & 31;
    const int et  = t >> 5;
    const int j04 = jt * 2;
    const int el0 = et * 4;    // 4 edges per thread

    // ---- stage 3: f1 = silu(t2 @ filt_w1 + fb1)   (M=32,N=256,K=64)
    {
        float acc[4][8];
        #pragma unroll
        for (int r = 0; r < 4; ++r)
            #pragma unroll
            for (int c = 0; c < 8; ++c) acc[r][c] = 0.f;
        for (int k4 = 0; k4 < 16; ++k4) {
            float4 a4[4];
            #pragma unroll
            for (int r = 0; r < 4; ++r)
                a4[r] = reinterpret_cast<float4*>(t2_s)[(el0 + r) * 16 + k4];
            #pragma unroll
            for (int q = 0; q < 4; ++q) {
                int k = k4 * 4 + q;
                float4 b0 = reinterpret_cast<const float4*>(filt_w1)[k * 64 + j04];
                float4 b1 = reinterpret_cast<const float4*>(filt_w1)[k * 64 + j04 + 1];
                float bb[8] = {b0.x, b0.y, b0.z, b0.w, b1.x, b1.y, b1.z, b1.w};
                #pragma unroll
                for (int r = 0; r < 4; ++r) {
                    float av = f4c(a4[r], q);
                    #pragma unroll
                    for (int c = 0; c < 8; ++c) acc[r][c] = fmaf(av, bb[c], acc[r][c]);
                }
            }
        }
        float4 fb0 = reinterpret_cast<const float4*>(filt_b1)[j04];
        float4 fb1 = reinterpret_cast<const float4*>(filt_b1)[j04 + 1];
        float fb[8] = {fb0.x, fb0.y, fb0.z, fb0.w, fb1.x, fb1.y, fb1.z, fb1.w};
        #pragma unroll
        for (int r = 0; r < 4; ++r) {
            float4 p0 = make_float4(silu_f(acc[r][0] + fb[0]), silu_f(acc[r][1] + fb[1]),
                                    silu_f(acc[r][2] + fb[2]), silu_f(acc[r][3] + fb[3]));
            float4 p1 = make_float4(silu_f(acc[r][4] + fb[4]), silu_f(acc[r][5] + fb[5]),
                                    silu_f(acc[r][6] + fb[6]), silu_f(acc[r][7] + fb[7]));
            reinterpret_cast<float4*>(f1_s)[(el0 + r) * 64 + j04]     = p0;
            reinterpret_cast<float4*>(f1_s)[(el0 + r) * 64 + j04 + 1] = p1;
        }
        __syncthreads();
    }

    // ---- stage 4: f2 = silu(f1 @ filt_w2 + fb2)   (M=32,N=256,K=256)
    {
        float acc[4][8];
        #pragma unroll
        for (int r = 0; r < 4; ++r)
            #pragma unroll
            for (int c = 0; c < 8; ++c) acc[r][c] = 0.f;
        for (int k4 = 0; k4 < 64; ++k4) {
            float4 a4[4];
            #pragma unroll
            for (int r = 0; r < 4; ++r)
                a4[r] = reinterpret_cast<float4*>(f1_s)[(el0 + r) * 64 + k4];
            #pragma unroll
            for (int q = 0; q < 4; ++q) {
                int k = k4 * 4 + q;
                float4 b0 = reinterpret_cast<const float4*>(filt_w2)[k * 64 + j04];
                float4 b1 = reinterpret_cast<const float4*>(filt_w2)[k * 64 + j04 + 1];
                float bb[8] = {b0.x, b0.y, b0.z, b0.w, b1.x, b1.y, b1.z, b1.w};
                #pragma unroll
                for (int r = 0; r < 4; ++r) {
                    float av = f4c(a4[r], q);
                    #pragma unroll
                    for (int c = 0; c < 8; ++c) acc[r][c] = fmaf(av, bb[c], acc[r][c]);
                }
            }
        }
        float4 fb0 = reinterpret_cast<const float4*>(filt_b2)[j04];
        float4 fb1 = reinterpret_cast<const float4*>(filt_b2)[j04 + 1];
        float fb[8] = {fb0.x, fb0.y, fb0.z, fb0.w, fb1.x, fb1.y, fb1.z, fb1.w};
        __syncthreads();   // all f1 reads done before overwriting f2_s region users? (f2_s holds dead t buffers; barrier orders f1-reads vs nothing—kept for clarity)
        #pragma unroll
        for (int r = 0; r < 4; ++r) {
            float4 p0 = make_float4(silu_f(acc[r][0] + fb[0]), silu_f(acc[r][1] + fb[1]),
                                    silu_f(acc[r][2] + fb[2]), silu_f(acc[r][3] + fb[3]));
            float4 p1 = make_float4(silu_f(acc[r][4] + fb[4]), silu_f(acc[r][5] + fb[5]),
                                    silu_f(acc[r][6] + fb[6]), silu_f(acc[r][7] + fb[7]));
            reinterpret_cast<float4*>(f2_s)[(el0 + r) * 64 + j04]     = p0;
            reinterpret_cast<float4*>(f2_s)[(el0 + r) * 64 + j04 + 1] = p1;
        }
        __syncthreads();
    }

    // ---- stage 5: W = f2 @ filt_w3 + fb3; msg = y[col]*W; atomic scatter
    {
        float acc[4][8];
        #pragma unroll
        for (int r = 0; r < 4; ++r)
            #pragma unroll
            for (int c = 0; c < 8; ++c) acc[r][c] = 0.f;
        for (int k4 = 0; k4 < 64; ++k4) {
            float4 a4[4];
            #pragma unroll
            for (int r = 0; r < 4; ++r)
                a4[r] = reinterpret_cast<float4*>(f2_s)[(el0 + r) * 64 + k4];
            #pragma unroll
            for (int q = 0; q < 4; ++q) {
                int k = k4 * 4 + q;
                float4 b0 = reinterpret_cast<const float4*>(filt_w3)[k * 64 + j04];
                float4 b1 = reinterpret_cast<const float4*>(filt_w3)[k * 64 + j04 + 1];
                float bb[8] = {b0.x, b0.y, b0.z, b0.w, b1.x, b1.y, b1.z, b1.w};
                #pragma unroll
                for (int r = 0; r < 4; ++r) {
                    float av = f4c(a4[r], q);
                    #pragma unroll
                    for (int c = 0; c < 8; ++c) acc[r][c] = fmaf(av, bb[c], acc[r][c]);
                }
            }
        }
        float4 fb0 = reinterpret_cast<const float4*>(filt_b3)[j04];
        float4 fb1 = reinterpret_cast<const float4*>(filt_b3)[j04 + 1];
        float fb[8] = {fb0.x, fb0.y, fb0.z, fb0.w, fb1.x, fb1.y, fb1.z, fb1.w};
        #pragma unroll
        for (int r = 0; r < 4; ++r) {
            int e  = el0 + r;
            int ge = e0 + e;
            if (ge < E) {
                int col = col_s[e];
                int row = row_s[e];
                float4 y0 = reinterpret_cast<const float4*>(y)[col * 64 + j04];
                float4 y1 = reinterpret_cast<const float4*>(y)[col * 64 + j04 + 1];
                float yy[8] = {y0.x, y0.y, y0.z, y0.w, y1.x, y1.y, y1.z, y1.w};
                float* ap = agg + row * 256 + jt * 8;
                #pragma unroll
                for (int c = 0; c < 8; ++c)
                    unsafeAtomicAdd(&ap[c], (acc[r][c] + fb[c]) * yy[c]);
            }
        }
    }
}

// ---------------------------------------------------------------------------
// LayerNorm: out0 = LN(x + agg) * g + b.   One wave per row.
// ---------------------------------------------------------------------------
__global__ __launch_bounds__(256)
void ln_kernel(const float* __restrict__ x, const float* __restrict__ agg,
               const float* __restrict__ g, const float* __restrict__ b,
               float* __restrict__ out0, int N)
{
    int lane = threadIdx.x & 63;
    int row  = blockIdx.x * 4 + (threadIdx.x >> 6);
    if (row >= N) return;
    float4 hx = reinterpret_cast<const float4*>(x)[row * 64 + lane];
    float4 ha = reinterpret_cast<const float4*>(agg)[row * 64 + lane];
    float4 h  = make_float4(hx.x + ha.x, hx.y + ha.y, hx.z + ha.z, hx.w + ha.w);
    float s  = h.x + h.y + h.z + h.w;
    float s2 = h.x * h.x + h.y * h.y + h.z * h.z + h.w * h.w;
    #pragma unroll
    for (int off = 32; off > 0; off >>= 1) {
        s  += __shfl_xor(s,  off, 64);
        s2 += __shfl_xor(s2, off, 64);
    }
    float mu  = s * (1.0f / 256.0f);
    float var = s2 * (1.0f / 256.0f) - mu * mu;
    float inv = rsqrtf(var + F_EPS_LN);
    float4 gv = reinterpret_cast<const float4*>(g)[lane];
    float4 bv = reinterpret_cast<const float4*>(b)[lane];
    float4 o;
    o.x = (h.x - mu) * inv * gv.x + bv.x;
    o.y = (h.y - mu) * inv * gv.y + bv.y;
    o.z = (h.z - mu) * inv * gv.z + bv.z;
    o.w = (h.w - mu) * inv * gv.w + bv.w;
    reinterpret_cast<float4*>(out0)[row * 64 + lane] = o;
}

// ---------------------------------------------------------------------------
extern "C" void kernel_launch(void* const* d_in, const int* in_sizes, int n_in,
                              void* d_out, int out_size, void* d_ws, size_t ws_size,
                              hipStream_t stream)
{
    const float* x       = (const float*)d_in[0];
    const int*   eidx    = (const int*)  d_in[1];
    const float* dist    = (const float*)d_in[2];
    const float* centers = (const float*)d_in[3];
    const float* widths  = (const float*)d_in[4];
    const float* rbf_w1  = (const float*)d_in[5];
    const float* rbf_b1  = (const float*)d_in[6];
    const float* rbf_w2  = (const float*)d_in[7];
    const float* rbf_b2  = (const float*)d_in[8];
    const float* filt_w1 = (const float*)d_in[9];
    const float* filt_b1 = (const float*)d_in[10];
    const float* filt_w2 = (const float*)d_in[11];
    const float* filt_b2 = (const float*)d_in[12];
    const float* filt_w3 = (const float*)d_in[13];
    const float* filt_b3 = (const float*)d_in[14];
    const float* node_w  = (const float*)d_in[15];
    const float* node_b  = (const float*)d_in[16];
    const float* ln_g    = (const float*)d_in[17];
    const float* ln_b    = (const float*)d_in[18];
    const float* gate_w  = (const float*)d_in[19];
    const float* gate_b  = (const float*)d_in[20];

    const int N = in_sizes[0] / 256;
    const int E = in_sizes[2];

    float* y_ws = (float*)d_ws;          // [N,256]; later reused for out0
    float* agg  = (float*)d_out;         // accumulate messages directly in d_out

    hipMemsetAsync(d_out, 0, (size_t)out_size * sizeof(float), stream);

    dim3 blk(256);
    gemm256_kernel<0><<<dim3((N + 63) / 64), blk, 0, stream>>>(x, node_w, node_b, y_ws, N);
    edge_kernel<<<dim3((E + 31) / 32), blk, 0, stream>>>(
        dist, eidx, centers, widths,
        rbf_w1, rbf_b1, rbf_w2, rbf_b2,
        filt_w1, filt_b1, filt_w2, filt_b2, filt_w3, filt_b3,
        y_ws, agg, E);
    ln_kernel<<<dim3((N + 3) / 4), blk, 0, stream>>>(x, agg, ln_g, ln_b, y_ws, N);
    gemm256_kernel<1><<<dim3((N + 63) / 64), blk, 0, stream>>>(y_ws, gate_w, gate_b, (float*)d_out, N);
}

// Round 2
// 1022.382 us; speedup vs baseline: 2.5851x; 2.5851x over previous
//
#include <hip/hip_runtime.h>
#include <hip/hip_bf16.h>
#include <math.h>

typedef __attribute__((ext_vector_type(8))) short bf16x8;
typedef __attribute__((ext_vector_type(4))) float f32x4;
typedef unsigned short ushort_t;

constexpr float F_CUTOFF = 10.0f;
constexpr float F_EPS_W  = 1e-5f;
constexpr float F_EPS_LN = 1e-5f;
constexpr float F_PI     = 3.14159265358979323846f;

__device__ __forceinline__ float silu_f(float v)   { return v / (1.0f + __expf(-v)); }
__device__ __forceinline__ float sigmoid_f(float v){ return 1.0f / (1.0f + __expf(-v)); }

__device__ __forceinline__ ushort_t f2bf(float f) {
    union { __hip_bfloat16 h; ushort_t u; } v; v.h = __float2bfloat16(f); return v.u;
}
__device__ __forceinline__ float bf2f(ushort_t u) {
    union { __hip_bfloat16 h; ushort_t u; } v; v.u = u; return __bfloat162float(v.h);
}

__device__ __forceinline__ float f4c(const float4& v, int q) {
    return q == 0 ? v.x : q == 1 ? v.y : q == 2 ? v.z : v.w;
}

// ---------------------------------------------------------------------------
// Weight convert+transpose: in fp32 [K][N] -> out bf16 [N][K].  K,N pow2.
// ---------------------------------------------------------------------------
__global__ void cvt_transpose_kernel(const float* __restrict__ in, ushort_t* __restrict__ out,
                                     int K, int N, int logK)
{
    int idx = blockIdx.x * 256 + threadIdx.x;
    if (idx >= K * N) return;
    int n = idx >> logK;
    int k = idx & (K - 1);
    out[idx] = f2bf(in[k * N + n]);
}

// ---------------------------------------------------------------------------
// y = x @ node_w + node_b, output bf16.  64-row tile, 8x8 micro-tile.
// ---------------------------------------------------------------------------
__global__ __launch_bounds__(256)
void gemm256_bf16_kernel(const float* __restrict__ A, const float* __restrict__ Wm,
                         const float* __restrict__ bias, ushort_t* __restrict__ out, int M)
{
    __shared__ float4 As4[64][64];
    const int t = threadIdx.x;
    const int row0 = blockIdx.x * 64;

    #pragma unroll
    for (int i = 0; i < 16; ++i) {
        int flat = t + i * 256;
        int r = flat >> 6, k4 = flat & 63;
        int row = row0 + r;
        float4 v = make_float4(0.f, 0.f, 0.f, 0.f);
        if (row < M) v = reinterpret_cast<const float4*>(A)[row * 64 + k4];
        As4[r][k4] = v;
    }
    __syncthreads();

    const int jt  = t & 31;
    const int et  = t >> 5;
    const int j04 = jt * 2;
    const int r0  = et * 8;

    float acc[8][8];
    #pragma unroll
    for (int r = 0; r < 8; ++r)
        #pragma unroll
        for (int c = 0; c < 8; ++c) acc[r][c] = 0.f;

    for (int k4 = 0; k4 < 64; ++k4) {
        float4 a4[8];
        #pragma unroll
        for (int r = 0; r < 8; ++r) a4[r] = As4[r0 + r][k4];
        #pragma unroll
        for (int q = 0; q < 4; ++q) {
            const int k = k4 * 4 + q;
            float4 b0 = reinterpret_cast<const float4*>(Wm)[k * 64 + j04];
            float4 b1 = reinterpret_cast<const float4*>(Wm)[k * 64 + j04 + 1];
            float bb[8] = {b0.x, b0.y, b0.z, b0.w, b1.x, b1.y, b1.z, b1.w};
            #pragma unroll
            for (int r = 0; r < 8; ++r) {
                float av = f4c(a4[r], q);
                #pragma unroll
                for (int c = 0; c < 8; ++c) acc[r][c] = fmaf(av, bb[c], acc[r][c]);
            }
        }
    }

    float4 bv0 = reinterpret_cast<const float4*>(bias)[j04];
    float4 bv1 = reinterpret_cast<const float4*>(bias)[j04 + 1];
    float bb[8] = {bv0.x, bv0.y, bv0.z, bv0.w, bv1.x, bv1.y, bv1.z, bv1.w};

    #pragma unroll
    for (int r = 0; r < 8; ++r) {
        int row = row0 + r0 + r;
        if (row >= M) continue;
        ushort_t o8[8];
        #pragma unroll
        for (int c = 0; c < 8; ++c) o8[c] = f2bf(acc[r][c] + bb[c]);
        *reinterpret_cast<uint4*>(out + (size_t)row * 256 + jt * 8) = *reinterpret_cast<uint4*>(o8);
    }
}

// ---------------------------------------------------------------------------
// Gate GEMM (fp32): out = A * sigmoid(A@W + b), in-place safe per 64-row block.
// ---------------------------------------------------------------------------
__global__ __launch_bounds__(256)
void gate_gemm_kernel(const float* __restrict__ A, const float* __restrict__ Wm,
                      const float* __restrict__ bias, float* __restrict__ out, int M)
{
    __shared__ float4 As4[64][64];
    const int t = threadIdx.x;
    const int row0 = blockIdx.x * 64;

    #pragma unroll
    for (int i = 0; i < 16; ++i) {
        int flat = t + i * 256;
        int r = flat >> 6, k4 = flat & 63;
        int row = row0 + r;
        float4 v = make_float4(0.f, 0.f, 0.f, 0.f);
        if (row < M) v = reinterpret_cast<const float4*>(A)[row * 64 + k4];
        As4[r][k4] = v;
    }
    __syncthreads();

    const int jt  = t & 31;
    const int et  = t >> 5;
    const int j04 = jt * 2;
    const int r0  = et * 8;

    float acc[8][8];
    #pragma unroll
    for (int r = 0; r < 8; ++r)
        #pragma unroll
        for (int c = 0; c < 8; ++c) acc[r][c] = 0.f;

    for (int k4 = 0; k4 < 64; ++k4) {
        float4 a4[8];
        #pragma unroll
        for (int r = 0; r < 8; ++r) a4[r] = As4[r0 + r][k4];
        #pragma unroll
        for (int q = 0; q < 4; ++q) {
            const int k = k4 * 4 + q;
            float4 b0 = reinterpret_cast<const float4*>(Wm)[k * 64 + j04];
            float4 b1 = reinterpret_cast<const float4*>(Wm)[k * 64 + j04 + 1];
            float bb[8] = {b0.x, b0.y, b0.z, b0.w, b1.x, b1.y, b1.z, b1.w};
            #pragma unroll
            for (int r = 0; r < 8; ++r) {
                float av = f4c(a4[r], q);
                #pragma unroll
                for (int c = 0; c < 8; ++c) acc[r][c] = fmaf(av, bb[c], acc[r][c]);
            }
        }
    }

    float4 bv0 = reinterpret_cast<const float4*>(bias)[j04];
    float4 bv1 = reinterpret_cast<const float4*>(bias)[j04 + 1];
    float bb[8] = {bv0.x, bv0.y, bv0.z, bv0.w, bv1.x, bv1.y, bv1.z, bv1.w};

    #pragma unroll
    for (int r = 0; r < 8; ++r) {
        int row = row0 + r0 + r;
        if (row >= M) continue;
        float4 a0 = As4[r0 + r][j04];
        float4 a1 = As4[r0 + r][j04 + 1];
        float aa[8] = {a0.x, a0.y, a0.z, a0.w, a1.x, a1.y, a1.z, a1.w};
        float o[8];
        #pragma unroll
        for (int c = 0; c < 8; ++c) o[c] = aa[c] * sigmoid_f(acc[r][c] + bb[c]);
        reinterpret_cast<float4*>(out)[row * 64 + j04]     = make_float4(o[0], o[1], o[2], o[3]);
        reinterpret_cast<float4*>(out)[row * 64 + j04 + 1] = make_float4(o[4], o[5], o[6], o[7]);
    }
}

// ---------------------------------------------------------------------------
// MFMA edge pipeline.
// 128 edges/block, 512 threads = 8 waves (2m x 4n), wave tile 64m x 64n.
// Activations ping-pong in LDS (pitch 512B/row, XOR-swizzled 16B units).
// Weights: bf16, transposed [N][K] in global (L2-resident), B-frag = 16B load.
// A-frag layout (16x16x32): lane q=l&15 -> row, k = 8*(l>>4)+j.
// C   layout: col n = l&15, row m = 4*(l>>4)+reg  [verified m89].
// ---------------------------------------------------------------------------
template<int KS, int NT, bool SILU>
__device__ __forceinline__ void mlp_stage(const unsigned char* in, unsigned char* out,
                                          const ushort_t* __restrict__ Wt,
                                          const float* __restrict__ bias,
                                          int wm, int wn, int g, int q)
{
    constexpr int K = KS * 32;
    f32x4 acc[4][NT];
    #pragma unroll
    for (int mt = 0; mt < 4; ++mt)
        #pragma unroll
        for (int nt = 0; nt < NT; ++nt) acc[mt][nt] = (f32x4){0.f, 0.f, 0.f, 0.f};

    #pragma unroll
    for (int kk = 0; kk < KS; ++kk) {
        bf16x8 a[4];
        #pragma unroll
        for (int mt = 0; mt < 4; ++mt) {
            int m = wm * 64 + mt * 16 + q;
            int unit = (4 * kk + g) ^ (m & 7);
            a[mt] = *reinterpret_cast<const bf16x8*>(in + m * 512 + unit * 16);
        }
        bf16x8 b[NT];
        #pragma unroll
        for (int nt = 0; nt < NT; ++nt) {
            int n = (wn * NT + nt) * 16 + q;
            b[nt] = *reinterpret_cast<const bf16x8*>(Wt + n * K + kk * 32 + g * 8);
        }
        #pragma unroll
        for (int mt = 0; mt < 4; ++mt)
            #pragma unroll
            for (int nt = 0; nt < NT; ++nt)
                acc[mt][nt] = __builtin_amdgcn_mfma_f32_16x16x32_bf16(a[mt], b[nt], acc[mt][nt], 0, 0, 0);
    }

    // C-layout -> A-layout redistribution: pair cols via shfl_xor(1), packed b32 writes.
    const bool evenq = (q & 1) == 0;
    #pragma unroll
    for (int nt = 0; nt < NT; ++nt) {
        int n0  = (wn * NT + nt) * 16 + q;
        int n_e = n0 & ~1;
        float2 bv = *reinterpret_cast<const float2*>(bias + n_e);
        #pragma unroll
        for (int mt = 0; mt < 4; ++mt) {
            float v[4], p[4];
            #pragma unroll
            for (int r = 0; r < 4; ++r) { v[r] = acc[mt][nt][r]; p[r] = __shfl_xor(v[r], 1, 64); }
            #pragma unroll
            for (int rr = 0; rr < 2; ++rr) {
                int r = evenq ? rr : (2 + rr);
                float lo = (evenq ? v[r] : p[r]) + bv.x;
                float hi = (evenq ? p[r] : v[r]) + bv.y;
                if (SILU) { lo = silu_f(lo); hi = silu_f(hi); }
                int m = wm * 64 + mt * 16 + 4 * g + r;
                unsigned u = (unsigned)f2bf(lo) | ((unsigned)f2bf(hi) << 16);
                int byte = m * 512 + (((n_e >> 3) ^ (m & 7)) << 4) + ((n_e & 7) * 2);
                *reinterpret_cast<unsigned*>(out + byte) = u;
            }
        }
    }
}

__global__ __launch_bounds__(512)
void edge_mfma_kernel(const float* __restrict__ dist, const int* __restrict__ eidx,
                      const float* __restrict__ centers, const float* __restrict__ widths,
                      const ushort_t* __restrict__ wt_rbf1, const float* __restrict__ rbf_b1,
                      const ushort_t* __restrict__ wt_rbf2, const float* __restrict__ rbf_b2,
                      const ushort_t* __restrict__ wt_f1, const float* __restrict__ filt_b1,
                      const ushort_t* __restrict__ wt_f2, const float* __restrict__ filt_b2,
                      const ushort_t* __restrict__ wt_f3, const float* __restrict__ filt_b3,
                      const ushort_t* __restrict__ y, float* __restrict__ agg, int E)
{
    extern __shared__ __align__(16) unsigned char smem[];
    unsigned char* bufA = smem;
    unsigned char* bufB = smem + 65536;

    const int t  = threadIdx.x;
    const int e0 = blockIdx.x * 128;
    const int w    = t >> 6;
    const int wm   = w >> 2, wn = w & 3;
    const int lane = t & 63;
    const int g = lane >> 4, q = lane & 15;

    // ---- S0: RBF features r[128][64] -> bufA
    {
        int e  = t >> 2;
        int k0 = (t & 3) * 16;
        int ge = e0 + e;
        float d = (ge < E) ? dist[ge] : F_CUTOFF;
        float env = (d < F_CUTOFF) ? 0.5f * (__cosf(d * (F_PI / F_CUTOFF)) + 1.0f) : 0.0f;
        unsigned char* rowp = bufA + e * 512;
        #pragma unroll
        for (int i = 0; i < 8; ++i) {
            int n = k0 + 2 * i;
            float c0 = centers[n],     w0 = fabsf(widths[n]) + F_EPS_W;
            float c1 = centers[n + 1], w1 = fabsf(widths[n + 1]) + F_EPS_W;
            float z0 = (d - c0) / w0, z1 = (d - c1) / w1;
            float r0 = env * __expf(-0.5f * z0 * z0);
            float r1 = env * __expf(-0.5f * z1 * z1);
            unsigned u = (unsigned)f2bf(r0) | ((unsigned)f2bf(r1) << 16);
            int byte = (((n >> 3) ^ (e & 7)) << 4) + ((n & 7) * 2);
            *reinterpret_cast<unsigned*>(rowp + byte) = u;
        }
    }
    __syncthreads();

    mlp_stage<2, 1, true >(bufA, bufB, wt_rbf1, rbf_b1, wm, wn, g, q);   // t1 = silu(r@w1+b1)
    __syncthreads();
    mlp_stage<2, 1, false>(bufB, bufA, wt_rbf2, rbf_b2, wm, wn, g, q);   // t2 = t1@w2+b2
    __syncthreads();
    mlp_stage<2, 4, true >(bufA, bufB, wt_f1, filt_b1, wm, wn, g, q);    // f1 = silu(t2@fw1+fb1)
    __syncthreads();
    mlp_stage<8, 4, true >(bufB, bufA, wt_f2, filt_b2, wm, wn, g, q);    // f2 = silu(f1@fw2+fb2)
    __syncthreads();

    // ---- final: Wf = f2@fw3+fb3; msg = y[col]*Wf; atomic scatter to agg
    {
        f32x4 acc[4][4];
        #pragma unroll
        for (int mt = 0; mt < 4; ++mt)
            #pragma unroll
            for (int nt = 0; nt < 4; ++nt) acc[mt][nt] = (f32x4){0.f, 0.f, 0.f, 0.f};

        #pragma unroll
        for (int kk = 0; kk < 8; ++kk) {
            bf16x8 a[4];
            #pragma unroll
            for (int mt = 0; mt < 4; ++mt) {
                int m = wm * 64 + mt * 16 + q;
                int unit = (4 * kk + g) ^ (m & 7);
                a[mt] = *reinterpret_cast<const bf16x8*>(bufA + m * 512 + unit * 16);
            }
            bf16x8 b[4];
            #pragma unroll
            for (int nt = 0; nt < 4; ++nt) {
                int n = (wn * 4 + nt) * 16 + q;
                b[nt] = *reinterpret_cast<const bf16x8*>(wt_f3 + n * 256 + kk * 32 + g * 8);
            }
            #pragma unroll
            for (int mt = 0; mt < 4; ++mt)
                #pragma unroll
                for (int nt = 0; nt < 4; ++nt)
                    acc[mt][nt] = __builtin_amdgcn_mfma_f32_16x16x32_bf16(a[mt], b[nt], acc[mt][nt], 0, 0, 0);
        }

        float bn[4];
        int   nn[4];
        #pragma unroll
        for (int nt = 0; nt < 4; ++nt) { nn[nt] = (wn * 4 + nt) * 16 + q; bn[nt] = filt_b3[nn[nt]]; }

        #pragma unroll
        for (int mt = 0; mt < 4; ++mt) {
            #pragma unroll
            for (int r = 0; r < 4; ++r) {
                int m  = wm * 64 + mt * 16 + 4 * g + r;
                int ge = e0 + m;
                if (ge < E) {
                    int rowi = eidx[ge];
                    int coli = eidx[E + ge];
                    const ushort_t* yrow = y + (size_t)coli * 256;
                    float* arow = agg + (size_t)rowi * 256;
                    #pragma unroll
                    for (int nt = 0; nt < 4; ++nt) {
                        float wv = acc[mt][nt][r] + bn[nt];
                        float yv = bf2f(yrow[nn[nt]]);
                        unsafeAtomicAdd(&arow[nn[nt]], wv * yv);
                    }
                }
            }
        }
    }
}

// ---------------------------------------------------------------------------
// LayerNorm in-place: d_out = LN(x + d_out) * g + b
// ---------------------------------------------------------------------------
__global__ __launch_bounds__(256)
void ln_kernel(const float* __restrict__ x, const float* __restrict__ agg,
               const float* __restrict__ g, const float* __restrict__ b,
               float* __restrict__ out0, int N)
{
    int lane = threadIdx.x & 63;
    int row  = blockIdx.x * 4 + (threadIdx.x >> 6);
    if (row >= N) return;
    float4 hx = reinterpret_cast<const float4*>(x)[row * 64 + lane];
    float4 ha = reinterpret_cast<const float4*>(agg)[row * 64 + lane];
    float4 h  = make_float4(hx.x + ha.x, hx.y + ha.y, hx.z + ha.z, hx.w + ha.w);
    float s  = h.x + h.y + h.z + h.w;
    float s2 = h.x * h.x + h.y * h.y + h.z * h.z + h.w * h.w;
    #pragma unroll
    for (int off = 32; off > 0; off >>= 1) {
        s  += __shfl_xor(s,  off, 64);
        s2 += __shfl_xor(s2, off, 64);
    }
    float mu  = s * (1.0f / 256.0f);
    float var = s2 * (1.0f / 256.0f) - mu * mu;
    float inv = rsqrtf(var + F_EPS_LN);
    float4 gv = reinterpret_cast<const float4*>(g)[lane];
    float4 bv = reinterpret_cast<const float4*>(b)[lane];
    float4 o;
    o.x = (h.x - mu) * inv * gv.x + bv.x;
    o.y = (h.y - mu) * inv * gv.y + bv.y;
    o.z = (h.z - mu) * inv * gv.z + bv.z;
    o.w = (h.w - mu) * inv * gv.w + bv.w;
    reinterpret_cast<float4*>(out0)[row * 64 + lane] = o;
}

// ---------------------------------------------------------------------------
extern "C" void kernel_launch(void* const* d_in, const int* in_sizes, int n_in,
                              void* d_out, int out_size, void* d_ws, size_t ws_size,
                              hipStream_t stream)
{
    const float* x       = (const float*)d_in[0];
    const int*   eidx    = (const int*)  d_in[1];
    const float* dist    = (const float*)d_in[2];
    const float* centers = (const float*)d_in[3];
    const float* widths  = (const float*)d_in[4];
    const float* rbf_w1  = (const float*)d_in[5];
    const float* rbf_b1  = (const float*)d_in[6];
    const float* rbf_w2  = (const float*)d_in[7];
    const float* rbf_b2  = (const float*)d_in[8];
    const float* filt_w1 = (const float*)d_in[9];
    const float* filt_b1 = (const float*)d_in[10];
    const float* filt_w2 = (const float*)d_in[11];
    const float* filt_b2 = (const float*)d_in[12];
    const float* filt_w3 = (const float*)d_in[13];
    const float* filt_b3 = (const float*)d_in[14];
    const float* node_w  = (const float*)d_in[15];
    const float* node_b  = (const float*)d_in[16];
    const float* ln_g    = (const float*)d_in[17];
    const float* ln_b    = (const float*)d_in[18];
    const float* gate_w  = (const float*)d_in[19];
    const float* gate_b  = (const float*)d_in[20];

    const int N = in_sizes[0] / 256;
    const int E = in_sizes[2];

    // ws layout: y bf16 [N,256], then transposed bf16 weights
    ushort_t* y_bf = (ushort_t*)d_ws;
    ushort_t* wt1  = y_bf + (size_t)N * 256;     // [64][64]
    ushort_t* wt2  = wt1 + 64 * 64;              // [64][64]
    ushort_t* wf1  = wt2 + 64 * 64;              // [256][64]
    ushort_t* wf2  = wf1 + 256 * 64;             // [256][256]
    ushort_t* wf3  = wf2 + 256 * 256;            // [256][256]

    float* agg = (float*)d_out;

    hipMemsetAsync(d_out, 0, (size_t)out_size * sizeof(float), stream);

    cvt_transpose_kernel<<<dim3((64 * 64 + 255) / 256),   256, 0, stream>>>(rbf_w1,  wt1, 64, 64, 6);
    cvt_transpose_kernel<<<dim3((64 * 64 + 255) / 256),   256, 0, stream>>>(rbf_w2,  wt2, 64, 64, 6);
    cvt_transpose_kernel<<<dim3((64 * 256 + 255) / 256),  256, 0, stream>>>(filt_w1, wf1, 64, 256, 6);
    cvt_transpose_kernel<<<dim3((256 * 256 + 255) / 256), 256, 0, stream>>>(filt_w2, wf2, 256, 256, 8);
    cvt_transpose_kernel<<<dim3((256 * 256 + 255) / 256), 256, 0, stream>>>(filt_w3, wf3, 256, 256, 8);

    gemm256_bf16_kernel<<<dim3((N + 63) / 64), 256, 0, stream>>>(x, node_w, node_b, y_bf, N);

    hipFuncSetAttribute((const void*)edge_mfma_kernel,
                        hipFuncAttributeMaxDynamicSharedMemorySize, 131072);
    edge_mfma_kernel<<<dim3((E + 127) / 128), 512, 131072, stream>>>(
        dist, eidx, centers, widths,
        wt1, rbf_b1, wt2, rbf_b2,
        wf1, filt_b1, wf2, filt_b2, wf3, filt_b3,
        y_bf, agg, E);

    ln_kernel<<<dim3((N + 3) / 4), 256, 0, stream>>>(x, agg, ln_g, ln_b, (float*)d_out, N);
    gate_gemm_kernel<<<dim3((N + 63) / 64), 256, 0, stream>>>((float*)d_out, gate_w, gate_b, (float*)d_out, N);
}

// Round 3
// 848.028 us; speedup vs baseline: 3.1166x; 1.2056x over previous
//
#include <hip/hip_runtime.h>
#include <hip/hip_bf16.h>
#include <math.h>

typedef __attribute__((ext_vector_type(8))) short bf16x8;
typedef __attribute__((ext_vector_type(4))) float f32x4;
typedef unsigned short ushort_t;

constexpr float F_CUTOFF = 10.0f;
constexpr float F_EPS_W  = 1e-5f;
constexpr float F_EPS_LN = 1e-5f;
constexpr float F_PI     = 3.14159265358979323846f;

__device__ __forceinline__ float silu_f(float v)   { return v / (1.0f + __expf(-v)); }
__device__ __forceinline__ float sigmoid_f(float v){ return 1.0f / (1.0f + __expf(-v)); }

__device__ __forceinline__ ushort_t f2bf(float f) {
    union { __hip_bfloat16 h; ushort_t u; } v; v.h = __float2bfloat16(f); return v.u;
}
__device__ __forceinline__ float bf2f(ushort_t u) {
    union { __hip_bfloat16 h; ushort_t u; } v; v.u = u; return __bfloat162float(v.h);
}

__device__ __forceinline__ float f4c(const float4& v, int q) {
    return q == 0 ? v.x : q == 1 ? v.y : q == 2 ? v.z : v.w;
}

// ---------------------------------------------------------------------------
// Weight convert+transpose: in fp32 [K][N] -> out bf16 [N][K].  K,N pow2.
// ---------------------------------------------------------------------------
__global__ void cvt_transpose_kernel(const float* __restrict__ in, ushort_t* __restrict__ out,
                                     int K, int N, int logK)
{
    int idx = blockIdx.x * 256 + threadIdx.x;
    if (idx >= K * N) return;
    int n = idx >> logK;
    int k = idx & (K - 1);
    out[idx] = f2bf(in[k * N + n]);
}

// ---------------------------------------------------------------------------
// wcomb[c][j] = sum_n rbf_w2[j][n] * filt_w1[n][c]   -> bf16 [256][64]
// (valid because there is NO activation between rbf_w2 and filt_w1)
// ---------------------------------------------------------------------------
__global__ void combine_w_kernel(const float* __restrict__ w2, const float* __restrict__ fw1,
                                 ushort_t* __restrict__ out)
{
    int idx = blockIdx.x * 256 + threadIdx.x;   // 16384 total
    int c = idx >> 6, j = idx & 63;
    float s = 0.f;
    #pragma unroll 8
    for (int n = 0; n < 64; ++n) s += w2[j * 64 + n] * fw1[n * 256 + c];
    out[idx] = f2bf(s);
}

__global__ void combine_b_kernel(const float* __restrict__ b2, const float* __restrict__ fw1,
                                 const float* __restrict__ fb1, float* __restrict__ out)
{
    int c = threadIdx.x;   // 256
    float s = fb1[c];
    #pragma unroll 8
    for (int n = 0; n < 64; ++n) s += b2[n] * fw1[n * 256 + c];
    out[c] = s;
}

// ---------------------------------------------------------------------------
// y = x @ node_w + node_b, output bf16.  64-row tile, 8x8 micro-tile.
// ---------------------------------------------------------------------------
__global__ __launch_bounds__(256)
void gemm256_bf16_kernel(const float* __restrict__ A, const float* __restrict__ Wm,
                         const float* __restrict__ bias, ushort_t* __restrict__ out, int M)
{
    __shared__ float4 As4[64][64];
    const int t = threadIdx.x;
    const int row0 = blockIdx.x * 64;

    #pragma unroll
    for (int i = 0; i < 16; ++i) {
        int flat = t + i * 256;
        int r = flat >> 6, k4 = flat & 63;
        int row = row0 + r;
        float4 v = make_float4(0.f, 0.f, 0.f, 0.f);
        if (row < M) v = reinterpret_cast<const float4*>(A)[row * 64 + k4];
        As4[r][k4] = v;
    }
    __syncthreads();

    const int jt  = t & 31;
    const int et  = t >> 5;
    const int j04 = jt * 2;
    const int r0  = et * 8;

    float acc[8][8];
    #pragma unroll
    for (int r = 0; r < 8; ++r)
        #pragma unroll
        for (int c = 0; c < 8; ++c) acc[r][c] = 0.f;

    for (int k4 = 0; k4 < 64; ++k4) {
        float4 a4[8];
        #pragma unroll
        for (int r = 0; r < 8; ++r) a4[r] = As4[r0 + r][k4];
        #pragma unroll
        for (int q = 0; q < 4; ++q) {
            const int k = k4 * 4 + q;
            float4 b0 = reinterpret_cast<const float4*>(Wm)[k * 64 + j04];
            float4 b1 = reinterpret_cast<const float4*>(Wm)[k * 64 + j04 + 1];
            float bb[8] = {b0.x, b0.y, b0.z, b0.w, b1.x, b1.y, b1.z, b1.w};
            #pragma unroll
            for (int r = 0; r < 8; ++r) {
                float av = f4c(a4[r], q);
                #pragma unroll
                for (int c = 0; c < 8; ++c) acc[r][c] = fmaf(av, bb[c], acc[r][c]);
            }
        }
    }

    float4 bv0 = reinterpret_cast<const float4*>(bias)[j04];
    float4 bv1 = reinterpret_cast<const float4*>(bias)[j04 + 1];
    float bb[8] = {bv0.x, bv0.y, bv0.z, bv0.w, bv1.x, bv1.y, bv1.z, bv1.w};

    #pragma unroll
    for (int r = 0; r < 8; ++r) {
        int row = row0 + r0 + r;
        if (row >= M) continue;
        ushort_t o8[8];
        #pragma unroll
        for (int c = 0; c < 8; ++c) o8[c] = f2bf(acc[r][c] + bb[c]);
        *reinterpret_cast<uint4*>(out + (size_t)row * 256 + jt * 8) = *reinterpret_cast<uint4*>(o8);
    }
}

// ---------------------------------------------------------------------------
// Gate GEMM (fp32): out = A * sigmoid(A@W + b), in-place safe per 64-row block.
// ---------------------------------------------------------------------------
__global__ __launch_bounds__(256)
void gate_gemm_kernel(const float* __restrict__ A, const float* __restrict__ Wm,
                      const float* __restrict__ bias, float* __restrict__ out, int M)
{
    __shared__ float4 As4[64][64];
    const int t = threadIdx.x;
    const int row0 = blockIdx.x * 64;

    #pragma unroll
    for (int i = 0; i < 16; ++i) {
        int flat = t + i * 256;
        int r = flat >> 6, k4 = flat & 63;
        int row = row0 + r;
        float4 v = make_float4(0.f, 0.f, 0.f, 0.f);
        if (row < M) v = reinterpret_cast<const float4*>(A)[row * 64 + k4];
        As4[r][k4] = v;
    }
    __syncthreads();

    const int jt  = t & 31;
    const int et  = t >> 5;
    const int j04 = jt * 2;
    const int r0  = et * 8;

    float acc[8][8];
    #pragma unroll
    for (int r = 0; r < 8; ++r)
        #pragma unroll
        for (int c = 0; c < 8; ++c) acc[r][c] = 0.f;

    for (int k4 = 0; k4 < 64; ++k4) {
        float4 a4[8];
        #pragma unroll
        for (int r = 0; r < 8; ++r) a4[r] = As4[r0 + r][k4];
        #pragma unroll
        for (int q = 0; q < 4; ++q) {
            const int k = k4 * 4 + q;
            float4 b0 = reinterpret_cast<const float4*>(Wm)[k * 64 + j04];
            float4 b1 = reinterpret_cast<const float4*>(Wm)[k * 64 + j04 + 1];
            float bb[8] = {b0.x, b0.y, b0.z, b0.w, b1.x, b1.y, b1.z, b1.w};
            #pragma unroll
            for (int r = 0; r < 8; ++r) {
                float av = f4c(a4[r], q);
                #pragma unroll
                for (int c = 0; c < 8; ++c) acc[r][c] = fmaf(av, bb[c], acc[r][c]);
            }
        }
    }

    float4 bv0 = reinterpret_cast<const float4*>(bias)[j04];
    float4 bv1 = reinterpret_cast<const float4*>(bias)[j04 + 1];
    float bb[8] = {bv0.x, bv0.y, bv0.z, bv0.w, bv1.x, bv1.y, bv1.z, bv1.w};

    #pragma unroll
    for (int r = 0; r < 8; ++r) {
        int row = row0 + r0 + r;
        if (row >= M) continue;
        float4 a0 = As4[r0 + r][j04];
        float4 a1 = As4[r0 + r][j04 + 1];
        float aa[8] = {a0.x, a0.y, a0.z, a0.w, a1.x, a1.y, a1.z, a1.w};
        float o[8];
        #pragma unroll
        for (int c = 0; c < 8; ++c) o[c] = aa[c] * sigmoid_f(acc[r][c] + bb[c]);
        reinterpret_cast<float4*>(out)[row * 64 + j04]     = make_float4(o[0], o[1], o[2], o[3]);
        reinterpret_cast<float4*>(out)[row * 64 + j04 + 1] = make_float4(o[4], o[5], o[6], o[7]);
    }
}

// ---------------------------------------------------------------------------
// MFMA edge pipeline.
// 64 edges/block, 512 threads = 8 waves (2m x 4n), wave tile 32m x 64n.
// LDS: two 32 KB buffers (64 rows x 512B, XOR-swizzled 16B units) -> 64 KB
// total -> 2 blocks/CU -> 4 waves/SIMD.
// ---------------------------------------------------------------------------
template<int KS, int NT, bool SILU>
__device__ __forceinline__ void mlp_stage(const unsigned char* in, unsigned char* out,
                                          const ushort_t* __restrict__ Wt,
                                          const float* __restrict__ bias,
                                          int wm, int wn, int g, int q)
{
    constexpr int K = KS * 32;
    f32x4 acc[2][NT];
    #pragma unroll
    for (int mt = 0; mt < 2; ++mt)
        #pragma unroll
        for (int nt = 0; nt < NT; ++nt) acc[mt][nt] = (f32x4){0.f, 0.f, 0.f, 0.f};

    #pragma unroll
    for (int kk = 0; kk < KS; ++kk) {
        bf16x8 b[NT];
        #pragma unroll
        for (int nt = 0; nt < NT; ++nt) {
            int n = (wn * NT + nt) * 16 + q;
            b[nt] = *reinterpret_cast<const bf16x8*>(Wt + n * K + kk * 32 + g * 8);
        }
        bf16x8 a[2];
        #pragma unroll
        for (int mt = 0; mt < 2; ++mt) {
            int m = wm * 32 + mt * 16 + q;
            int unit = (4 * kk + g) ^ (m & 7);
            a[mt] = *reinterpret_cast<const bf16x8*>(in + m * 512 + unit * 16);
        }
        #pragma unroll
        for (int mt = 0; mt < 2; ++mt)
            #pragma unroll
            for (int nt = 0; nt < NT; ++nt)
                acc[mt][nt] = __builtin_amdgcn_mfma_f32_16x16x32_bf16(a[mt], b[nt], acc[mt][nt], 0, 0, 0);
    }

    // C-layout -> A-layout redistribution: pair cols via shfl_xor(1), packed b32 writes.
    const bool evenq = (q & 1) == 0;
    #pragma unroll
    for (int nt = 0; nt < NT; ++nt) {
        int n0  = (wn * NT + nt) * 16 + q;
        int n_e = n0 & ~1;
        float2 bv = *reinterpret_cast<const float2*>(bias + n_e);
        #pragma unroll
        for (int mt = 0; mt < 2; ++mt) {
            float v[4], p[4];
            #pragma unroll
            for (int r = 0; r < 4; ++r) { v[r] = acc[mt][nt][r]; p[r] = __shfl_xor(v[r], 1, 64); }
            #pragma unroll
            for (int rr = 0; rr < 2; ++rr) {
                int r = evenq ? rr : (2 + rr);
                float lo = (evenq ? v[r] : p[r]) + bv.x;
                float hi = (evenq ? p[r] : v[r]) + bv.y;
                if (SILU) { lo = silu_f(lo); hi = silu_f(hi); }
                int m = wm * 32 + mt * 16 + 4 * g + r;
                unsigned u = (unsigned)f2bf(lo) | ((unsigned)f2bf(hi) << 16);
                int byte = m * 512 + (((n_e >> 3) ^ (m & 7)) << 4) + ((n_e & 7) * 2);
                *reinterpret_cast<unsigned*>(out + byte) = u;
            }
        }
    }
}

__global__ __launch_bounds__(512, 4)
void edge_mfma_kernel(const float* __restrict__ dist, const int* __restrict__ eidx,
                      const float* __restrict__ centers, const float* __restrict__ widths,
                      const ushort_t* __restrict__ wt_rbf1, const float* __restrict__ rbf_b1,
                      const ushort_t* __restrict__ wt_comb, const float* __restrict__ b_comb,
                      const ushort_t* __restrict__ wt_f2, const float* __restrict__ filt_b2,
                      const ushort_t* __restrict__ wt_f3, const float* __restrict__ filt_b3,
                      const ushort_t* __restrict__ y, float* __restrict__ agg, int E)
{
    __shared__ __align__(16) unsigned char bufA[32768];
    __shared__ __align__(16) unsigned char bufB[32768];

    const int t  = threadIdx.x;
    const int e0 = blockIdx.x * 64;
    const int w    = t >> 6;
    const int wm   = w >> 2, wn = w & 3;
    const int lane = t & 63;
    const int g = lane >> 4, q = lane & 15;

    // ---- S0: RBF features r[64][64] -> bufA   (8 threads per edge, 8 cols each)
    {
        int e  = t >> 3;
        int k0 = (t & 7) * 8;
        int ge = e0 + e;
        float d = (ge < E) ? dist[ge] : F_CUTOFF;
        float env = (d < F_CUTOFF) ? 0.5f * (__cosf(d * (F_PI / F_CUTOFF)) + 1.0f) : 0.0f;
        unsigned char* rowp = bufA + e * 512;
        #pragma unroll
        for (int i = 0; i < 4; ++i) {
            int n = k0 + 2 * i;
            float c0 = centers[n],     w0 = fabsf(widths[n]) + F_EPS_W;
            float c1 = centers[n + 1], w1 = fabsf(widths[n + 1]) + F_EPS_W;
            float z0 = (d - c0) / w0, z1 = (d - c1) / w1;
            float r0 = env * __expf(-0.5f * z0 * z0);
            float r1 = env * __expf(-0.5f * z1 * z1);
            unsigned u = (unsigned)f2bf(r0) | ((unsigned)f2bf(r1) << 16);
            int byte = (((n >> 3) ^ (e & 7)) << 4) + ((n & 7) * 2);
            *reinterpret_cast<unsigned*>(rowp + byte) = u;
        }
    }
    __syncthreads();

    mlp_stage<2, 1, true>(bufA, bufB, wt_rbf1, rbf_b1, wm, wn, g, q);  // t1 = silu(r@w1+b1)
    __syncthreads();
    mlp_stage<2, 4, true>(bufB, bufA, wt_comb, b_comb, wm, wn, g, q);  // f1 = silu(t1@wcomb+bcomb)
    __syncthreads();
    mlp_stage<8, 4, true>(bufA, bufB, wt_f2, filt_b2, wm, wn, g, q);   // f2 = silu(f1@fw2+fb2)
    __syncthreads();

    // ---- final: Wf = f2@fw3+fb3; msg = y[col]*Wf; atomic scatter to agg
    {
        f32x4 acc[2][4];
        #pragma unroll
        for (int mt = 0; mt < 2; ++mt)
            #pragma unroll
            for (int nt = 0; nt < 4; ++nt) acc[mt][nt] = (f32x4){0.f, 0.f, 0.f, 0.f};

        #pragma unroll
        for (int kk = 0; kk < 8; ++kk) {
            bf16x8 b[4];
            #pragma unroll
            for (int nt = 0; nt < 4; ++nt) {
                int n = (wn * 4 + nt) * 16 + q;
                b[nt] = *reinterpret_cast<const bf16x8*>(wt_f3 + n * 256 + kk * 32 + g * 8);
            }
            bf16x8 a[2];
            #pragma unroll
            for (int mt = 0; mt < 2; ++mt) {
                int m = wm * 32 + mt * 16 + q;
                int unit = (4 * kk + g) ^ (m & 7);
                a[mt] = *reinterpret_cast<const bf16x8*>(bufB + m * 512 + unit * 16);
            }
            #pragma unroll
            for (int mt = 0; mt < 2; ++mt)
                #pragma unroll
                for (int nt = 0; nt < 4; ++nt)
                    acc[mt][nt] = __builtin_amdgcn_mfma_f32_16x16x32_bf16(a[mt], b[nt], acc[mt][nt], 0, 0, 0);
        }

        float bn[4];
        int   nn[4];
        #pragma unroll
        for (int nt = 0; nt < 4; ++nt) { nn[nt] = (wn * 4 + nt) * 16 + q; bn[nt] = filt_b3[nn[nt]]; }

        #pragma unroll
        for (int mt = 0; mt < 2; ++mt) {
            #pragma unroll
            for (int r = 0; r < 4; ++r) {
                int m  = wm * 32 + mt * 16 + 4 * g + r;
                int ge = e0 + m;
                if (ge < E) {
                    int rowi = eidx[ge];
                    int coli = eidx[E + ge];
                    const ushort_t* yrow = y + (size_t)coli * 256;
                    float* arow = agg + (size_t)rowi * 256;
                    #pragma unroll
                    for (int nt = 0; nt < 4; ++nt) {
                        float wv = acc[mt][nt][r] + bn[nt];
                        float yv = bf2f(yrow[nn[nt]]);
                        unsafeAtomicAdd(&arow[nn[nt]], wv * yv);
                    }
                }
            }
        }
    }
}

// ---------------------------------------------------------------------------
// LayerNorm in-place: d_out = LN(x + d_out) * g + b
// ---------------------------------------------------------------------------
__global__ __launch_bounds__(256)
void ln_kernel(const float* __restrict__ x, const float* __restrict__ agg,
               const float* __restrict__ g, const float* __restrict__ b,
               float* __restrict__ out0, int N)
{
    int lane = threadIdx.x & 63;
    int row  = blockIdx.x * 4 + (threadIdx.x >> 6);
    if (row >= N) return;
    float4 hx = reinterpret_cast<const float4*>(x)[row * 64 + lane];
    float4 ha = reinterpret_cast<const float4*>(agg)[row * 64 + lane];
    float4 h  = make_float4(hx.x + ha.x, hx.y + ha.y, hx.z + ha.z, hx.w + ha.w);
    float s  = h.x + h.y + h.z + h.w;
    float s2 = h.x * h.x + h.y * h.y + h.z * h.z + h.w * h.w;
    #pragma unroll
    for (int off = 32; off > 0; off >>= 1) {
        s  += __shfl_xor(s,  off, 64);
        s2 += __shfl_xor(s2, off, 64);
    }
    float mu  = s * (1.0f / 256.0f);
    float var = s2 * (1.0f / 256.0f) - mu * mu;
    float inv = rsqrtf(var + F_EPS_LN);
    float4 gv = reinterpret_cast<const float4*>(g)[lane];
    float4 bv = reinterpret_cast<const float4*>(b)[lane];
    float4 o;
    o.x = (h.x - mu) * inv * gv.x + bv.x;
    o.y = (h.y - mu) * inv * gv.y + bv.y;
    o.z = (h.z - mu) * inv * gv.z + bv.z;
    o.w = (h.w - mu) * inv * gv.w + bv.w;
    reinterpret_cast<float4*>(out0)[row * 64 + lane] = o;
}

// ---------------------------------------------------------------------------
extern "C" void kernel_launch(void* const* d_in, const int* in_sizes, int n_in,
                              void* d_out, int out_size, void* d_ws, size_t ws_size,
                              hipStream_t stream)
{
    const float* x       = (const float*)d_in[0];
    const int*   eidx    = (const int*)  d_in[1];
    const float* dist    = (const float*)d_in[2];
    const float* centers = (const float*)d_in[3];
    const float* widths  = (const float*)d_in[4];
    const float* rbf_w1  = (const float*)d_in[5];
    const float* rbf_b1  = (const float*)d_in[6];
    const float* rbf_w2  = (const float*)d_in[7];
    const float* rbf_b2  = (const float*)d_in[8];
    const float* filt_w1 = (const float*)d_in[9];
    const float* filt_b1 = (const float*)d_in[10];
    const float* filt_w2 = (const float*)d_in[11];
    const float* filt_b2 = (const float*)d_in[12];
    const float* filt_w3 = (const float*)d_in[13];
    const float* filt_b3 = (const float*)d_in[14];
    const float* node_w  = (const float*)d_in[15];
    const float* node_b  = (const float*)d_in[16];
    const float* ln_g    = (const float*)d_in[17];
    const float* ln_b    = (const float*)d_in[18];
    const float* gate_w  = (const float*)d_in[19];
    const float* gate_b  = (const float*)d_in[20];

    const int N = in_sizes[0] / 256;
    const int E = in_sizes[2];

    // ws layout: y bf16 [N,256], then transposed bf16 weights + combined bias
    ushort_t* y_bf   = (ushort_t*)d_ws;
    ushort_t* wt1    = y_bf + (size_t)N * 256;   // [64][64]
    ushort_t* wcomb  = wt1 + 64 * 64;            // [256][64]
    ushort_t* wf2    = wcomb + 256 * 64;         // [256][256]
    ushort_t* wf3    = wf2 + 256 * 256;          // [256][256]
    float*    bcomb  = (float*)(wf3 + 256 * 256);// [256]

    float* agg = (float*)d_out;

    hipMemsetAsync(d_out, 0, (size_t)out_size * sizeof(float), stream);

    cvt_transpose_kernel<<<dim3((64 * 64 + 255) / 256),   256, 0, stream>>>(rbf_w1,  wt1, 64, 64, 6);
    combine_w_kernel<<<dim3(64), 256, 0, stream>>>(rbf_w2, filt_w1, wcomb);
    combine_b_kernel<<<dim3(1), 256, 0, stream>>>(rbf_b2, filt_w1, filt_b1, bcomb);
    cvt_transpose_kernel<<<dim3((256 * 256 + 255) / 256), 256, 0, stream>>>(filt_w2, wf2, 256, 256, 8);
    cvt_transpose_kernel<<<dim3((256 * 256 + 255) / 256), 256, 0, stream>>>(filt_w3, wf3, 256, 256, 8);

    gemm256_bf16_kernel<<<dim3((N + 63) / 64), 256, 0, stream>>>(x, node_w, node_b, y_bf, N);

    edge_mfma_kernel<<<dim3((E + 63) / 64), 512, 0, stream>>>(
        dist, eidx, centers, widths,
        wt1, rbf_b1, wcomb, bcomb,
        wf2, filt_b2, wf3, filt_b3,
        y_bf, agg, E);

    ln_kernel<<<dim3((N + 3) / 4), 256, 0, stream>>>(x, agg, ln_g, ln_b, (float*)d_out, N);
    gate_gemm_kernel<<<dim3((N + 63) / 64), 256, 0, stream>>>((float*)d_out, gate_w, gate_b, (float*)d_out, N);
}

// Round 4
// 824.363 us; speedup vs baseline: 3.2061x; 1.0287x over previous
//
#include <hip/hip_runtime.h>
#include <hip/hip_bf16.h>
#include <math.h>

typedef __attribute__((ext_vector_type(8))) short bf16x8;
typedef __attribute__((ext_vector_type(4))) float f32x4;
typedef unsigned short ushort_t;

constexpr float F_CUTOFF = 10.0f;
constexpr float F_EPS_W  = 1e-5f;
constexpr float F_EPS_LN = 1e-5f;
constexpr float F_PI     = 3.14159265358979323846f;

__device__ __forceinline__ float silu_f(float v)   { return v / (1.0f + __expf(-v)); }
__device__ __forceinline__ float sigmoid_f(float v){ return 1.0f / (1.0f + __expf(-v)); }

__device__ __forceinline__ ushort_t f2bf(float f) {
    union { __hip_bfloat16 h; ushort_t u; } v; v.h = __float2bfloat16(f); return v.u;
}
__device__ __forceinline__ float bf2f(ushort_t u) {
    union { __hip_bfloat16 h; ushort_t u; } v; v.u = u; return __bfloat162float(v.h);
}

__device__ __forceinline__ float f4c(const float4& v, int q) {
    return q == 0 ? v.x : q == 1 ? v.y : q == 2 ? v.z : v.w;
}

// ---------------------------------------------------------------------------
// Weight convert+transpose: in fp32 [K][N] -> out bf16 [N][K].  K,N pow2.
// ---------------------------------------------------------------------------
__global__ void cvt_transpose_kernel(const float* __restrict__ in, ushort_t* __restrict__ out,
                                     int K, int N, int logK)
{
    int idx = blockIdx.x * 256 + threadIdx.x;
    if (idx >= K * N) return;
    int n = idx >> logK;
    int k = idx & (K - 1);
    out[idx] = f2bf(in[k * N + n]);
}

// ---------------------------------------------------------------------------
// wcomb[c][j] = sum_n rbf_w2[j][n] * filt_w1[n][c]   -> bf16 [256][64]
// (valid because there is NO activation between rbf_w2 and filt_w1)
// ---------------------------------------------------------------------------
__global__ void combine_w_kernel(const float* __restrict__ w2, const float* __restrict__ fw1,
                                 ushort_t* __restrict__ out)
{
    int idx = blockIdx.x * 256 + threadIdx.x;   // 16384 total
    int c = idx >> 6, j = idx & 63;
    float s = 0.f;
    #pragma unroll 8
    for (int n = 0; n < 64; ++n) s += w2[j * 64 + n] * fw1[n * 256 + c];
    out[idx] = f2bf(s);
}

__global__ void combine_b_kernel(const float* __restrict__ b2, const float* __restrict__ fw1,
                                 const float* __restrict__ fb1, float* __restrict__ out)
{
    int c = threadIdx.x;   // 256
    float s = fb1[c];
    #pragma unroll 8
    for (int n = 0; n < 64; ++n) s += b2[n] * fw1[n * 256 + c];
    out[c] = s;
}

// ---------------------------------------------------------------------------
// y = x @ node_w + node_b, output bf16.  64-row tile, 8x8 micro-tile.
// ---------------------------------------------------------------------------
__global__ __launch_bounds__(256)
void gemm256_bf16_kernel(const float* __restrict__ A, const float* __restrict__ Wm,
                         const float* __restrict__ bias, ushort_t* __restrict__ out, int M)
{
    __shared__ float4 As4[64][64];
    const int t = threadIdx.x;
    const int row0 = blockIdx.x * 64;

    #pragma unroll
    for (int i = 0; i < 16; ++i) {
        int flat = t + i * 256;
        int r = flat >> 6, k4 = flat & 63;
        int row = row0 + r;
        float4 v = make_float4(0.f, 0.f, 0.f, 0.f);
        if (row < M) v = reinterpret_cast<const float4*>(A)[row * 64 + k4];
        As4[r][k4] = v;
    }
    __syncthreads();

    const int jt  = t & 31;
    const int et  = t >> 5;
    const int j04 = jt * 2;
    const int r0  = et * 8;

    float acc[8][8];
    #pragma unroll
    for (int r = 0; r < 8; ++r)
        #pragma unroll
        for (int c = 0; c < 8; ++c) acc[r][c] = 0.f;

    for (int k4 = 0; k4 < 64; ++k4) {
        float4 a4[8];
        #pragma unroll
        for (int r = 0; r < 8; ++r) a4[r] = As4[r0 + r][k4];
        #pragma unroll
        for (int q = 0; q < 4; ++q) {
            const int k = k4 * 4 + q;
            float4 b0 = reinterpret_cast<const float4*>(Wm)[k * 64 + j04];
            float4 b1 = reinterpret_cast<const float4*>(Wm)[k * 64 + j04 + 1];
            float bb[8] = {b0.x, b0.y, b0.z, b0.w, b1.x, b1.y, b1.z, b1.w};
            #pragma unroll
            for (int r = 0; r < 8; ++r) {
                float av = f4c(a4[r], q);
                #pragma unroll
                for (int c = 0; c < 8; ++c) acc[r][c] = fmaf(av, bb[c], acc[r][c]);
            }
        }
    }

    float4 bv0 = reinterpret_cast<const float4*>(bias)[j04];
    float4 bv1 = reinterpret_cast<const float4*>(bias)[j04 + 1];
    float bb[8] = {bv0.x, bv0.y, bv0.z, bv0.w, bv1.x, bv1.y, bv1.z, bv1.w};

    #pragma unroll
    for (int r = 0; r < 8; ++r) {
        int row = row0 + r0 + r;
        if (row >= M) continue;
        ushort_t o8[8];
        #pragma unroll
        for (int c = 0; c < 8; ++c) o8[c] = f2bf(acc[r][c] + bb[c]);
        *reinterpret_cast<uint4*>(out + (size_t)row * 256 + jt * 8) = *reinterpret_cast<uint4*>(o8);
    }
}

// ---------------------------------------------------------------------------
// Gate GEMM (fp32): out = A * sigmoid(A@W + b), in-place safe per 64-row block.
// ---------------------------------------------------------------------------
__global__ __launch_bounds__(256)
void gate_gemm_kernel(const float* __restrict__ A, const float* __restrict__ Wm,
                      const float* __restrict__ bias, float* __restrict__ out, int M)
{
    __shared__ float4 As4[64][64];
    const int t = threadIdx.x;
    const int row0 = blockIdx.x * 64;

    #pragma unroll
    for (int i = 0; i < 16; ++i) {
        int flat = t + i * 256;
        int r = flat >> 6, k4 = flat & 63;
        int row = row0 + r;
        float4 v = make_float4(0.f, 0.f, 0.f, 0.f);
        if (row < M) v = reinterpret_cast<const float4*>(A)[row * 64 + k4];
        As4[r][k4] = v;
    }
    __syncthreads();

    const int jt  = t & 31;
    const int et  = t >> 5;
    const int j04 = jt * 2;
    const int r0  = et * 8;

    float acc[8][8];
    #pragma unroll
    for (int r = 0; r < 8; ++r)
        #pragma unroll
        for (int c = 0; c < 8; ++c) acc[r][c] = 0.f;

    for (int k4 = 0; k4 < 64; ++k4) {
        float4 a4[8];
        #pragma unroll
        for (int r = 0; r < 8; ++r) a4[r] = As4[r0 + r][k4];
        #pragma unroll
        for (int q = 0; q < 4; ++q) {
            const int k = k4 * 4 + q;
            float4 b0 = reinterpret_cast<const float4*>(Wm)[k * 64 + j04];
            float4 b1 = reinterpret_cast<const float4*>(Wm)[k * 64 + j04 + 1];
            float bb[8] = {b0.x, b0.y, b0.z, b0.w, b1.x, b1.y, b1.z, b1.w};
            #pragma unroll
            for (int r = 0; r < 8; ++r) {
                float av = f4c(a4[r], q);
                #pragma unroll
                for (int c = 0; c < 8; ++c) acc[r][c] = fmaf(av, bb[c], acc[r][c]);
            }
        }
    }

    float4 bv0 = reinterpret_cast<const float4*>(bias)[j04];
    float4 bv1 = reinterpret_cast<const float4*>(bias)[j04 + 1];
    float bb[8] = {bv0.x, bv0.y, bv0.z, bv0.w, bv1.x, bv1.y, bv1.z, bv1.w};

    #pragma unroll
    for (int r = 0; r < 8; ++r) {
        int row = row0 + r0 + r;
        if (row >= M) continue;
        float4 a0 = As4[r0 + r][j04];
        float4 a1 = As4[r0 + r][j04 + 1];
        float aa[8] = {a0.x, a0.y, a0.z, a0.w, a1.x, a1.y, a1.z, a1.w};
        float o[8];
        #pragma unroll
        for (int c = 0; c < 8; ++c) o[c] = aa[c] * sigmoid_f(acc[r][c] + bb[c]);
        reinterpret_cast<float4*>(out)[row * 64 + j04]     = make_float4(o[0], o[1], o[2], o[3]);
        reinterpret_cast<float4*>(out)[row * 64 + j04 + 1] = make_float4(o[4], o[5], o[6], o[7]);
    }
}

// ---------------------------------------------------------------------------
// MFMA edge pipeline.
// 32 edges/block, 256 threads = 4 waves (1m x 4n), wave tile 32m x 64n.
// LDS: two 16 KB buffers (32 rows x 512B, XOR-swizzled 16B units) -> 32 KB
// -> 4 independent blocks/CU at 4 waves/SIMD.
// y[col] gather hoisted to block start (regs), parked into bufA for the final
// stage (bufA is dead after stage-3 reads).
// ---------------------------------------------------------------------------
template<int KS, int NT, bool SILU>
__device__ __forceinline__ void mlp_stage(const unsigned char* in, unsigned char* out,
                                          const ushort_t* __restrict__ Wt,
                                          const float* __restrict__ bias,
                                          int wn, int g, int q)
{
    constexpr int K = KS * 32;
    f32x4 acc[2][NT];
    #pragma unroll
    for (int mt = 0; mt < 2; ++mt)
        #pragma unroll
        for (int nt = 0; nt < NT; ++nt) acc[mt][nt] = (f32x4){0.f, 0.f, 0.f, 0.f};

    #pragma unroll
    for (int kk = 0; kk < KS; ++kk) {
        bf16x8 b[NT];
        #pragma unroll
        for (int nt = 0; nt < NT; ++nt) {
            int n = (wn * NT + nt) * 16 + q;
            b[nt] = *reinterpret_cast<const bf16x8*>(Wt + n * K + kk * 32 + g * 8);
        }
        bf16x8 a[2];
        #pragma unroll
        for (int mt = 0; mt < 2; ++mt) {
            int m = mt * 16 + q;
            int unit = (4 * kk + g) ^ (m & 7);
            a[mt] = *reinterpret_cast<const bf16x8*>(in + m * 512 + unit * 16);
        }
        #pragma unroll
        for (int mt = 0; mt < 2; ++mt)
            #pragma unroll
            for (int nt = 0; nt < NT; ++nt)
                acc[mt][nt] = __builtin_amdgcn_mfma_f32_16x16x32_bf16(a[mt], b[nt], acc[mt][nt], 0, 0, 0);
    }

    // C-layout -> A-layout redistribution: pair cols via shfl_xor(1), packed b32 writes.
    const bool evenq = (q & 1) == 0;
    #pragma unroll
    for (int nt = 0; nt < NT; ++nt) {
        int n0  = (wn * NT + nt) * 16 + q;
        int n_e = n0 & ~1;
        float2 bv = *reinterpret_cast<const float2*>(bias + n_e);
        #pragma unroll
        for (int mt = 0; mt < 2; ++mt) {
            float v[4], p[4];
            #pragma unroll
            for (int r = 0; r < 4; ++r) { v[r] = acc[mt][nt][r]; p[r] = __shfl_xor(v[r], 1, 64); }
            #pragma unroll
            for (int rr = 0; rr < 2; ++rr) {
                int r = evenq ? rr : (2 + rr);
                float lo = (evenq ? v[r] : p[r]) + bv.x;
                float hi = (evenq ? p[r] : v[r]) + bv.y;
                if (SILU) { lo = silu_f(lo); hi = silu_f(hi); }
                int m = mt * 16 + 4 * g + r;
                unsigned u = (unsigned)f2bf(lo) | ((unsigned)f2bf(hi) << 16);
                int byte = m * 512 + (((n_e >> 3) ^ (m & 7)) << 4) + ((n_e & 7) * 2);
                *reinterpret_cast<unsigned*>(out + byte) = u;
            }
        }
    }
}

__global__ __launch_bounds__(256, 4)
void edge_mfma_kernel(const float* __restrict__ dist, const int* __restrict__ eidx,
                      const float* __restrict__ centers, const float* __restrict__ widths,
                      const ushort_t* __restrict__ wt_rbf1, const float* __restrict__ rbf_b1,
                      const ushort_t* __restrict__ wt_comb, const float* __restrict__ b_comb,
                      const ushort_t* __restrict__ wt_f2, const float* __restrict__ filt_b2,
                      const ushort_t* __restrict__ wt_f3, const float* __restrict__ filt_b3,
                      const ushort_t* __restrict__ y, float* __restrict__ agg, int E)
{
    __shared__ __align__(16) unsigned char bufA[16384];
    __shared__ __align__(16) unsigned char bufB[16384];

    const int t  = threadIdx.x;
    const int e0 = blockIdx.x * 32;
    const int wn   = t >> 6;
    const int lane = t & 63;
    const int g = lane >> 4, q = lane & 15;

    // ---- y prefetch: thread t owns edge e_own = t>>3, 16B chunks (t&7)+8i.
    const int e_own  = t >> 3;
    const int chunk  = t & 7;
    const int ge_own = e0 + e_own;
    const int col_own = (ge_own < E) ? eidx[E + ge_own] : 0;
    uint4 yv[4];
    #pragma unroll
    for (int i = 0; i < 4; ++i)
        yv[i] = *reinterpret_cast<const uint4*>(y + (size_t)col_own * 256 + (i * 8 + chunk) * 8);

    // ---- S0: RBF features r[32][64] -> bufA   (8 threads per edge, 8 cols each)
    {
        float d = (ge_own < E) ? dist[ge_own] : F_CUTOFF;
        float env = (d < F_CUTOFF) ? 0.5f * (__cosf(d * (F_PI / F_CUTOFF)) + 1.0f) : 0.0f;
        unsigned char* rowp = bufA + e_own * 512;
        int k0 = chunk * 8;
        #pragma unroll
        for (int i = 0; i < 4; ++i) {
            int n = k0 + 2 * i;
            float c0 = centers[n],     w0 = fabsf(widths[n]) + F_EPS_W;
            float c1 = centers[n + 1], w1 = fabsf(widths[n + 1]) + F_EPS_W;
            float z0 = (d - c0) / w0, z1 = (d - c1) / w1;
            float r0 = env * __expf(-0.5f * z0 * z0);
            float r1 = env * __expf(-0.5f * z1 * z1);
            unsigned u = (unsigned)f2bf(r0) | ((unsigned)f2bf(r1) << 16);
            int byte = (((n >> 3) ^ (e_own & 7)) << 4) + ((n & 7) * 2);
            *reinterpret_cast<unsigned*>(rowp + byte) = u;
        }
    }
    __syncthreads();

    mlp_stage<2, 1, true>(bufA, bufB, wt_rbf1, rbf_b1, wn, g, q);  // t1 = silu(r@w1+b1)
    __syncthreads();
    mlp_stage<2, 4, true>(bufB, bufA, wt_comb, b_comb, wn, g, q);  // f1 = silu(t1@wcomb+bcomb)
    __syncthreads();
    mlp_stage<8, 4, true>(bufA, bufB, wt_f2, filt_b2, wn, g, q);   // f2 = silu(f1@fw2+fb2)
    __syncthreads();   // all reads of bufA (f1) complete -> bufA reusable for y

    // ---- park prefetched y into bufA (linear layout, row 512B)
    #pragma unroll
    for (int i = 0; i < 4; ++i)
        *reinterpret_cast<uint4*>(bufA + e_own * 512 + (i * 8 + chunk) * 16) = yv[i];
    __syncthreads();

    // ---- final: Wf = f2@fw3+fb3; msg = y_lds * Wf; atomic scatter to agg
    {
        f32x4 acc[2][4];
        #pragma unroll
        for (int mt = 0; mt < 2; ++mt)
            #pragma unroll
            for (int nt = 0; nt < 4; ++nt) acc[mt][nt] = (f32x4){0.f, 0.f, 0.f, 0.f};

        #pragma unroll
        for (int kk = 0; kk < 8; ++kk) {
            bf16x8 b[4];
            #pragma unroll
            for (int nt = 0; nt < 4; ++nt) {
                int n = (wn * 4 + nt) * 16 + q;
                b[nt] = *reinterpret_cast<const bf16x8*>(wt_f3 + n * 256 + kk * 32 + g * 8);
            }
            bf16x8 a[2];
            #pragma unroll
            for (int mt = 0; mt < 2; ++mt) {
                int m = mt * 16 + q;
                int unit = (4 * kk + g) ^ (m & 7);
                a[mt] = *reinterpret_cast<const bf16x8*>(bufB + m * 512 + unit * 16);
            }
            #pragma unroll
            for (int mt = 0; mt < 2; ++mt)
                #pragma unroll
                for (int nt = 0; nt < 4; ++nt)
                    acc[mt][nt] = __builtin_amdgcn_mfma_f32_16x16x32_bf16(a[mt], b[nt], acc[mt][nt], 0, 0, 0);
        }

        float bn[4];
        int   nn[4];
        #pragma unroll
        for (int nt = 0; nt < 4; ++nt) { nn[nt] = (wn * 4 + nt) * 16 + q; bn[nt] = filt_b3[nn[nt]]; }

        #pragma unroll
        for (int mt = 0; mt < 2; ++mt) {
            #pragma unroll
            for (int r = 0; r < 4; ++r) {
                int m  = mt * 16 + 4 * g + r;
                int ge = e0 + m;
                if (ge < E) {
                    int rowi = eidx[ge];
                    float* arow = agg + (size_t)rowi * 256;
                    const unsigned char* yrow = bufA + m * 512;
                    #pragma unroll
                    for (int nt = 0; nt < 4; ++nt) {
                        float wv = acc[mt][nt][r] + bn[nt];
                        float yvv = bf2f(*reinterpret_cast<const ushort_t*>(yrow + nn[nt] * 2));
                        unsafeAtomicAdd(&arow[nn[nt]], wv * yvv);
                    }
                }
            }
        }
    }
}

// ---------------------------------------------------------------------------
// LayerNorm in-place: d_out = LN(x + d_out) * g + b
// ---------------------------------------------------------------------------
__global__ __launch_bounds__(256)
void ln_kernel(const float* __restrict__ x, const float* __restrict__ agg,
               const float* __restrict__ g, const float* __restrict__ b,
               float* __restrict__ out0, int N)
{
    int lane = threadIdx.x & 63;
    int row  = blockIdx.x * 4 + (threadIdx.x >> 6);
    if (row >= N) return;
    float4 hx = reinterpret_cast<const float4*>(x)[row * 64 + lane];
    float4 ha = reinterpret_cast<const float4*>(agg)[row * 64 + lane];
    float4 h  = make_float4(hx.x + ha.x, hx.y + ha.y, hx.z + ha.z, hx.w + ha.w);
    float s  = h.x + h.y + h.z + h.w;
    float s2 = h.x * h.x + h.y * h.y + h.z * h.z + h.w * h.w;
    #pragma unroll
    for (int off = 32; off > 0; off >>= 1) {
        s  += __shfl_xor(s,  off, 64);
        s2 += __shfl_xor(s2, off, 64);
    }
    float mu  = s * (1.0f / 256.0f);
    float var = s2 * (1.0f / 256.0f) - mu * mu;
    float inv = rsqrtf(var + F_EPS_LN);
    float4 gv = reinterpret_cast<const float4*>(g)[lane];
    float4 bv = reinterpret_cast<const float4*>(b)[lane];
    float4 o;
    o.x = (h.x - mu) * inv * gv.x + bv.x;
    o.y = (h.y - mu) * inv * gv.y + bv.y;
    o.z = (h.z - mu) * inv * gv.z + bv.z;
    o.w = (h.w - mu) * inv * gv.w + bv.w;
    reinterpret_cast<float4*>(out0)[row * 64 + lane] = o;
}

// ---------------------------------------------------------------------------
extern "C" void kernel_launch(void* const* d_in, const int* in_sizes, int n_in,
                              void* d_out, int out_size, void* d_ws, size_t ws_size,
                              hipStream_t stream)
{
    const float* x       = (const float*)d_in[0];
    const int*   eidx    = (const int*)  d_in[1];
    const float* dist    = (const float*)d_in[2];
    const float* centers = (const float*)d_in[3];
    const float* widths  = (const float*)d_in[4];
    const float* rbf_w1  = (const float*)d_in[5];
    const float* rbf_b1  = (const float*)d_in[6];
    const float* rbf_w2  = (const float*)d_in[7];
    const float* rbf_b2  = (const float*)d_in[8];
    const float* filt_w1 = (const float*)d_in[9];
    const float* filt_b1 = (const float*)d_in[10];
    const float* filt_w2 = (const float*)d_in[11];
    const float* filt_b2 = (const float*)d_in[12];
    const float* filt_w3 = (const float*)d_in[13];
    const float* filt_b3 = (const float*)d_in[14];
    const float* node_w  = (const float*)d_in[15];
    const float* node_b  = (const float*)d_in[16];
    const float* ln_g    = (const float*)d_in[17];
    const float* ln_b    = (const float*)d_in[18];
    const float* gate_w  = (const float*)d_in[19];
    const float* gate_b  = (const float*)d_in[20];

    const int N = in_sizes[0] / 256;
    const int E = in_sizes[2];

    // ws layout: y bf16 [N,256], then transposed bf16 weights + combined bias
    ushort_t* y_bf   = (ushort_t*)d_ws;
    ushort_t* wt1    = y_bf + (size_t)N * 256;   // [64][64]
    ushort_t* wcomb  = wt1 + 64 * 64;            // [256][64]
    ushort_t* wf2    = wcomb + 256 * 64;         // [256][256]
    ushort_t* wf3    = wf2 + 256 * 256;          // [256][256]
    float*    bcomb  = (float*)(wf3 + 256 * 256);// [256]

    float* agg = (float*)d_out;

    hipMemsetAsync(d_out, 0, (size_t)out_size * sizeof(float), stream);

    cvt_transpose_kernel<<<dim3((64 * 64 + 255) / 256),   256, 0, stream>>>(rbf_w1,  wt1, 64, 64, 6);
    combine_w_kernel<<<dim3(64), 256, 0, stream>>>(rbf_w2, filt_w1, wcomb);
    combine_b_kernel<<<dim3(1), 256, 0, stream>>>(rbf_b2, filt_w1, filt_b1, bcomb);
    cvt_transpose_kernel<<<dim3((256 * 256 + 255) / 256), 256, 0, stream>>>(filt_w2, wf2, 256, 256, 8);
    cvt_transpose_kernel<<<dim3((256 * 256 + 255) / 256), 256, 0, stream>>>(filt_w3, wf3, 256, 256, 8);

    gemm256_bf16_kernel<<<dim3((N + 63) / 64), 256, 0, stream>>>(x, node_w, node_b, y_bf, N);

    edge_mfma_kernel<<<dim3((E + 31) / 32), 256, 0, stream>>>(
        dist, eidx, centers, widths,
        wt1, rbf_b1, wcomb, bcomb,
        wf2, filt_b2, wf3, filt_b3,
        y_bf, agg, E);

    ln_kernel<<<dim3((N + 3) / 4), 256, 0, stream>>>(x, agg, ln_g, ln_b, (float*)d_out, N);
    gate_gemm_kernel<<<dim3((N + 63) / 64), 256, 0, stream>>>((float*)d_out, gate_w, gate_b, (float*)d_out, N);
}

// Round 5
// 822.838 us; speedup vs baseline: 3.2120x; 1.0019x over previous
//
#include <hip/hip_runtime.h>
#include <hip/hip_bf16.h>
#include <math.h>

typedef __attribute__((ext_vector_type(8))) short bf16x8;
typedef __attribute__((ext_vector_type(4))) float f32x4;
typedef unsigned short ushort_t;

constexpr float F_CUTOFF = 10.0f;
constexpr float F_EPS_W  = 1e-5f;
constexpr float F_EPS_LN = 1e-5f;
constexpr float F_PI     = 3.14159265358979323846f;

__device__ __forceinline__ float silu_f(float v)   { return v / (1.0f + __expf(-v)); }
__device__ __forceinline__ float sigmoid_f(float v){ return 1.0f / (1.0f + __expf(-v)); }

__device__ __forceinline__ ushort_t f2bf(float f) {
    union { __hip_bfloat16 h; ushort_t u; } v; v.h = __float2bfloat16(f); return v.u;
}
__device__ __forceinline__ float bf2f(ushort_t u) {
    union { __hip_bfloat16 h; ushort_t u; } v; v.u = u; return __bfloat162float(v.h);
}

__device__ __forceinline__ float f4c(const float4& v, int q) {
    return q == 0 ? v.x : q == 1 ? v.y : q == 2 ? v.z : v.w;
}

// ---------------------------------------------------------------------------
// CSR build kernels
// ---------------------------------------------------------------------------
__global__ void count_kernel(const int* __restrict__ eidx, int* __restrict__ cnt, int E)
{
    int e = blockIdx.x * 256 + threadIdx.x;
    if (e < E) atomicAdd(&cnt[eidx[e]], 1);
}

__global__ __launch_bounds__(1024)
void scan_kernel(const int* __restrict__ cnt, int* __restrict__ start,
                 int* __restrict__ cursor, int N)
{
    __shared__ int part[1024];
    const int tid = threadIdx.x;
    const int C = (N + 1023) >> 10;
    const int base = tid * C;
    int s = 0;
    for (int i = 0; i < C; ++i) {
        int idx = base + i;
        if (idx < N) s += cnt[idx];
    }
    part[tid] = s;
    __syncthreads();
    for (int off = 1; off < 1024; off <<= 1) {
        int v = (tid >= off) ? part[tid - off] : 0;
        __syncthreads();
        part[tid] += v;
        __syncthreads();
    }
    int run = part[tid] - s;   // exclusive prefix
    for (int i = 0; i < C; ++i) {
        int idx = base + i;
        if (idx < N) {
            start[idx]  = run;
            cursor[idx] = run;
            run += cnt[idx];
        }
    }
    if (tid == 1023) start[N] = part[1023];
}

__global__ void scatter_kernel(const int* __restrict__ eidx, int* __restrict__ cursor,
                               int* __restrict__ slot, int E)
{
    int e = blockIdx.x * 256 + threadIdx.x;
    if (e < E) slot[e] = atomicAdd(&cursor[eidx[e]], 1);
}

// ---------------------------------------------------------------------------
// Weight convert+transpose: in fp32 [K][N] -> out bf16 [N][K].  K,N pow2.
// ---------------------------------------------------------------------------
__global__ void cvt_transpose_kernel(const float* __restrict__ in, ushort_t* __restrict__ out,
                                     int K, int N, int logK)
{
    int idx = blockIdx.x * 256 + threadIdx.x;
    if (idx >= K * N) return;
    int n = idx >> logK;
    int k = idx & (K - 1);
    out[idx] = f2bf(in[k * N + n]);
}

// ---------------------------------------------------------------------------
// wcomb[c][j] = sum_n rbf_w2[j][n] * filt_w1[n][c]   -> bf16 [256][64]
// ---------------------------------------------------------------------------
__global__ void combine_w_kernel(const float* __restrict__ w2, const float* __restrict__ fw1,
                                 ushort_t* __restrict__ out)
{
    int idx = blockIdx.x * 256 + threadIdx.x;   // 16384 total
    int c = idx >> 6, j = idx & 63;
    float s = 0.f;
    #pragma unroll 8
    for (int n = 0; n < 64; ++n) s += w2[j * 64 + n] * fw1[n * 256 + c];
    out[idx] = f2bf(s);
}

__global__ void combine_b_kernel(const float* __restrict__ b2, const float* __restrict__ fw1,
                                 const float* __restrict__ fb1, float* __restrict__ out)
{
    int c = threadIdx.x;   // 256
    float s = fb1[c];
    #pragma unroll 8
    for (int n = 0; n < 64; ++n) s += b2[n] * fw1[n * 256 + c];
    out[c] = s;
}

// ---------------------------------------------------------------------------
// y = x @ node_w + node_b, output bf16.  64-row tile, 8x8 micro-tile.
// ---------------------------------------------------------------------------
__global__ __launch_bounds__(256)
void gemm256_bf16_kernel(const float* __restrict__ A, const float* __restrict__ Wm,
                         const float* __restrict__ bias, ushort_t* __restrict__ out, int M)
{
    __shared__ float4 As4[64][64];
    const int t = threadIdx.x;
    const int row0 = blockIdx.x * 64;

    #pragma unroll
    for (int i = 0; i < 16; ++i) {
        int flat = t + i * 256;
        int r = flat >> 6, k4 = flat & 63;
        int row = row0 + r;
        float4 v = make_float4(0.f, 0.f, 0.f, 0.f);
        if (row < M) v = reinterpret_cast<const float4*>(A)[row * 64 + k4];
        As4[r][k4] = v;
    }
    __syncthreads();

    const int jt  = t & 31;
    const int et  = t >> 5;
    const int j04 = jt * 2;
    const int r0  = et * 8;

    float acc[8][8];
    #pragma unroll
    for (int r = 0; r < 8; ++r)
        #pragma unroll
        for (int c = 0; c < 8; ++c) acc[r][c] = 0.f;

    for (int k4 = 0; k4 < 64; ++k4) {
        float4 a4[8];
        #pragma unroll
        for (int r = 0; r < 8; ++r) a4[r] = As4[r0 + r][k4];
        #pragma unroll
        for (int q = 0; q < 4; ++q) {
            const int k = k4 * 4 + q;
            float4 b0 = reinterpret_cast<const float4*>(Wm)[k * 64 + j04];
            float4 b1 = reinterpret_cast<const float4*>(Wm)[k * 64 + j04 + 1];
            float bb[8] = {b0.x, b0.y, b0.z, b0.w, b1.x, b1.y, b1.z, b1.w};
            #pragma unroll
            for (int r = 0; r < 8; ++r) {
                float av = f4c(a4[r], q);
                #pragma unroll
                for (int c = 0; c < 8; ++c) acc[r][c] = fmaf(av, bb[c], acc[r][c]);
            }
        }
    }

    float4 bv0 = reinterpret_cast<const float4*>(bias)[j04];
    float4 bv1 = reinterpret_cast<const float4*>(bias)[j04 + 1];
    float bb[8] = {bv0.x, bv0.y, bv0.z, bv0.w, bv1.x, bv1.y, bv1.z, bv1.w};

    #pragma unroll
    for (int r = 0; r < 8; ++r) {
        int row = row0 + r0 + r;
        if (row >= M) continue;
        ushort_t o8[8];
        #pragma unroll
        for (int c = 0; c < 8; ++c) o8[c] = f2bf(acc[r][c] + bb[c]);
        *reinterpret_cast<uint4*>(out + (size_t)row * 256 + jt * 8) = *reinterpret_cast<uint4*>(o8);
    }
}

// ---------------------------------------------------------------------------
// Gate GEMM (fp32): out = A * sigmoid(A@W + b), in-place safe per 64-row block.
// ---------------------------------------------------------------------------
__global__ __launch_bounds__(256)
void gate_gemm_kernel(const float* __restrict__ A, const float* __restrict__ Wm,
                      const float* __restrict__ bias, float* __restrict__ out, int M)
{
    __shared__ float4 As4[64][64];
    const int t = threadIdx.x;
    const int row0 = blockIdx.x * 64;

    #pragma unroll
    for (int i = 0; i < 16; ++i) {
        int flat = t + i * 256;
        int r = flat >> 6, k4 = flat & 63;
        int row = row0 + r;
        float4 v = make_float4(0.f, 0.f, 0.f, 0.f);
        if (row < M) v = reinterpret_cast<const float4*>(A)[row * 64 + k4];
        As4[r][k4] = v;
    }
    __syncthreads();

    const int jt  = t & 31;
    const int et  = t >> 5;
    const int j04 = jt * 2;
    const int r0  = et * 8;

    float acc[8][8];
    #pragma unroll
    for (int r = 0; r < 8; ++r)
        #pragma unroll
        for (int c = 0; c < 8; ++c) acc[r][c] = 0.f;

    for (int k4 = 0; k4 < 64; ++k4) {
        float4 a4[8];
        #pragma unroll
        for (int r = 0; r < 8; ++r) a4[r] = As4[r0 + r][k4];
        #pragma unroll
        for (int q = 0; q < 4; ++q) {
            const int k = k4 * 4 + q;
            float4 b0 = reinterpret_cast<const float4*>(Wm)[k * 64 + j04];
            float4 b1 = reinterpret_cast<const float4*>(Wm)[k * 64 + j04 + 1];
            float bb[8] = {b0.x, b0.y, b0.z, b0.w, b1.x, b1.y, b1.z, b1.w};
            #pragma unroll
            for (int r = 0; r < 8; ++r) {
                float av = f4c(a4[r], q);
                #pragma unroll
                for (int c = 0; c < 8; ++c) acc[r][c] = fmaf(av, bb[c], acc[r][c]);
            }
        }
    }

    float4 bv0 = reinterpret_cast<const float4*>(bias)[j04];
    float4 bv1 = reinterpret_cast<const float4*>(bias)[j04 + 1];
    float bb[8] = {bv0.x, bv0.y, bv0.z, bv0.w, bv1.x, bv1.y, bv1.z, bv1.w};

    #pragma unroll
    for (int r = 0; r < 8; ++r) {
        int row = row0 + r0 + r;
        if (row >= M) continue;
        float4 a0 = As4[r0 + r][j04];
        float4 a1 = As4[r0 + r][j04 + 1];
        float aa[8] = {a0.x, a0.y, a0.z, a0.w, a1.x, a1.y, a1.z, a1.w};
        float o[8];
        #pragma unroll
        for (int c = 0; c < 8; ++c) o[c] = aa[c] * sigmoid_f(acc[r][c] + bb[c]);
        reinterpret_cast<float4*>(out)[row * 64 + j04]     = make_float4(o[0], o[1], o[2], o[3]);
        reinterpret_cast<float4*>(out)[row * 64 + j04 + 1] = make_float4(o[4], o[5], o[6], o[7]);
    }
}

// ---------------------------------------------------------------------------
// MFMA edge pipeline.  32 edges/block, 256 threads = 4 waves (1m x 4n).
// TWO=1: write msg rows (f32) to CSR slots.  TWO=0: atomic scatter (fallback).
// ---------------------------------------------------------------------------
template<int KS, int NT, bool SILU>
__device__ __forceinline__ void mlp_stage(const unsigned char* in, unsigned char* out,
                                          const ushort_t* __restrict__ Wt,
                                          const float* __restrict__ bias,
                                          int wn, int g, int q)
{
    constexpr int K = KS * 32;
    f32x4 acc[2][NT];
    #pragma unroll
    for (int mt = 0; mt < 2; ++mt)
        #pragma unroll
        for (int nt = 0; nt < NT; ++nt) acc[mt][nt] = (f32x4){0.f, 0.f, 0.f, 0.f};

    #pragma unroll
    for (int kk = 0; kk < KS; ++kk) {
        bf16x8 b[NT];
        #pragma unroll
        for (int nt = 0; nt < NT; ++nt) {
            int n = (wn * NT + nt) * 16 + q;
            b[nt] = *reinterpret_cast<const bf16x8*>(Wt + n * K + kk * 32 + g * 8);
        }
        bf16x8 a[2];
        #pragma unroll
        for (int mt = 0; mt < 2; ++mt) {
            int m = mt * 16 + q;
            int unit = (4 * kk + g) ^ (m & 7);
            a[mt] = *reinterpret_cast<const bf16x8*>(in + m * 512 + unit * 16);
        }
        #pragma unroll
        for (int mt = 0; mt < 2; ++mt)
            #pragma unroll
            for (int nt = 0; nt < NT; ++nt)
                acc[mt][nt] = __builtin_amdgcn_mfma_f32_16x16x32_bf16(a[mt], b[nt], acc[mt][nt], 0, 0, 0);
    }

    const bool evenq = (q & 1) == 0;
    #pragma unroll
    for (int nt = 0; nt < NT; ++nt) {
        int n0  = (wn * NT + nt) * 16 + q;
        int n_e = n0 & ~1;
        float2 bv = *reinterpret_cast<const float2*>(bias + n_e);
        #pragma unroll
        for (int mt = 0; mt < 2; ++mt) {
            float v[4], p[4];
            #pragma unroll
            for (int r = 0; r < 4; ++r) { v[r] = acc[mt][nt][r]; p[r] = __shfl_xor(v[r], 1, 64); }
            #pragma unroll
            for (int rr = 0; rr < 2; ++rr) {
                int r = evenq ? rr : (2 + rr);
                float lo = (evenq ? v[r] : p[r]) + bv.x;
                float hi = (evenq ? p[r] : v[r]) + bv.y;
                if (SILU) { lo = silu_f(lo); hi = silu_f(hi); }
                int m = mt * 16 + 4 * g + r;
                unsigned u = (unsigned)f2bf(lo) | ((unsigned)f2bf(hi) << 16);
                int byte = m * 512 + (((n_e >> 3) ^ (m & 7)) << 4) + ((n_e & 7) * 2);
                *reinterpret_cast<unsigned*>(out + byte) = u;
            }
        }
    }
}

template<int TWO>
__global__ __launch_bounds__(256, 4)
void edge_mfma_kernel(const float* __restrict__ dist, const int* __restrict__ eidx,
                      const float* __restrict__ centers, const float* __restrict__ widths,
                      const ushort_t* __restrict__ wt_rbf1, const float* __restrict__ rbf_b1,
                      const ushort_t* __restrict__ wt_comb, const float* __restrict__ b_comb,
                      const ushort_t* __restrict__ wt_f2, const float* __restrict__ filt_b2,
                      const ushort_t* __restrict__ wt_f3, const float* __restrict__ filt_b3,
                      const ushort_t* __restrict__ y, const int* __restrict__ slot,
                      float* __restrict__ dst, int E)
{
    __shared__ __align__(16) unsigned char bufA[16384];
    __shared__ __align__(16) unsigned char bufB[16384];
    __shared__ int rs_s[32];   // slot (TWO) or row (fallback)

    const int t  = threadIdx.x;
    const int e0 = blockIdx.x * 32;
    const int wn   = t >> 6;
    const int lane = t & 63;
    const int g = lane >> 4, q = lane & 15;

    if (t < 32) {
        int ge = e0 + t;
        if (TWO) rs_s[t] = (ge < E) ? slot[ge] : 0;
        else     rs_s[t] = (ge < E) ? eidx[ge] : 0;
    }

    // ---- y prefetch: thread t owns edge e_own = t>>3, 16B chunks (t&7)+8i.
    const int e_own  = t >> 3;
    const int chunk  = t & 7;
    const int ge_own = e0 + e_own;
    const int col_own = (ge_own < E) ? eidx[E + ge_own] : 0;
    uint4 yv[4];
    #pragma unroll
    for (int i = 0; i < 4; ++i)
        yv[i] = *reinterpret_cast<const uint4*>(y + (size_t)col_own * 256 + (i * 8 + chunk) * 8);

    // ---- S0: RBF features r[32][64] -> bufA
    {
        float d = (ge_own < E) ? dist[ge_own] : F_CUTOFF;
        float env = (d < F_CUTOFF) ? 0.5f * (__cosf(d * (F_PI / F_CUTOFF)) + 1.0f) : 0.0f;
        unsigned char* rowp = bufA + e_own * 512;
        int k0 = chunk * 8;
        #pragma unroll
        for (int i = 0; i < 4; ++i) {
            int n = k0 + 2 * i;
            float c0 = centers[n],     w0 = fabsf(widths[n]) + F_EPS_W;
            float c1 = centers[n + 1], w1 = fabsf(widths[n + 1]) + F_EPS_W;
            float z0 = (d - c0) / w0, z1 = (d - c1) / w1;
            float r0 = env * __expf(-0.5f * z0 * z0);
            float r1 = env * __expf(-0.5f * z1 * z1);
            unsigned u = (unsigned)f2bf(r0) | ((unsigned)f2bf(r1) << 16);
            int byte = (((n >> 3) ^ (e_own & 7)) << 4) + ((n & 7) * 2);
            *reinterpret_cast<unsigned*>(rowp + byte) = u;
        }
    }
    __syncthreads();

    mlp_stage<2, 1, true>(bufA, bufB, wt_rbf1, rbf_b1, wn, g, q);  // t1 = silu(r@w1+b1)
    __syncthreads();
    mlp_stage<2, 4, true>(bufB, bufA, wt_comb, b_comb, wn, g, q);  // f1 = silu(t1@wcomb+bcomb)
    __syncthreads();
    mlp_stage<8, 4, true>(bufA, bufB, wt_f2, filt_b2, wn, g, q);   // f2 = silu(f1@fw2+fb2)
    __syncthreads();   // bufA (f1) dead -> reuse for y

    #pragma unroll
    for (int i = 0; i < 4; ++i)
        *reinterpret_cast<uint4*>(bufA + e_own * 512 + (i * 8 + chunk) * 16) = yv[i];
    __syncthreads();

    // ---- final: Wf = f2@fw3+fb3; msg = y_lds * Wf; store/scatter
    {
        f32x4 acc[2][4];
        #pragma unroll
        for (int mt = 0; mt < 2; ++mt)
            #pragma unroll
            for (int nt = 0; nt < 4; ++nt) acc[mt][nt] = (f32x4){0.f, 0.f, 0.f, 0.f};

        #pragma unroll
        for (int kk = 0; kk < 8; ++kk) {
            bf16x8 b[4];
            #pragma unroll
            for (int nt = 0; nt < 4; ++nt) {
                int n = (wn * 4 + nt) * 16 + q;
                b[nt] = *reinterpret_cast<const bf16x8*>(wt_f3 + n * 256 + kk * 32 + g * 8);
            }
            bf16x8 a[2];
            #pragma unroll
            for (int mt = 0; mt < 2; ++mt) {
                int m = mt * 16 + q;
                int unit = (4 * kk + g) ^ (m & 7);
                a[mt] = *reinterpret_cast<const bf16x8*>(bufB + m * 512 + unit * 16);
            }
            #pragma unroll
            for (int mt = 0; mt < 2; ++mt)
                #pragma unroll
                for (int nt = 0; nt < 4; ++nt)
                    acc[mt][nt] = __builtin_amdgcn_mfma_f32_16x16x32_bf16(a[mt], b[nt], acc[mt][nt], 0, 0, 0);
        }

        float bn[4];
        int   nn[4];
        #pragma unroll
        for (int nt = 0; nt < 4; ++nt) { nn[nt] = (wn * 4 + nt) * 16 + q; bn[nt] = filt_b3[nn[nt]]; }

        #pragma unroll
        for (int mt = 0; mt < 2; ++mt) {
            #pragma unroll
            for (int r = 0; r < 4; ++r) {
                int m  = mt * 16 + 4 * g + r;
                int ge = e0 + m;
                if (ge < E) {
                    const unsigned char* yrow = bufA + m * 512;
                    if (TWO) {
                        float* mrow = dst + (size_t)rs_s[m] * 256;
                        #pragma unroll
                        for (int nt = 0; nt < 4; ++nt) {
                            float wv = acc[mt][nt][r] + bn[nt];
                            float yvv = bf2f(*reinterpret_cast<const ushort_t*>(yrow + nn[nt] * 2));
                            mrow[nn[nt]] = wv * yvv;
                        }
                    } else {
                        float* arow = dst + (size_t)rs_s[m] * 256;
                        #pragma unroll
                        for (int nt = 0; nt < 4; ++nt) {
                            float wv = acc[mt][nt][r] + bn[nt];
                            float yvv = bf2f(*reinterpret_cast<const ushort_t*>(yrow + nn[nt] * 2));
                            unsafeAtomicAdd(&arow[nn[nt]], wv * yvv);
                        }
                    }
                }
            }
        }
    }
}

// ---------------------------------------------------------------------------
// agg + residual + LayerNorm: out0 = LN(x + sum(msg rows)) * g + b
// One wave per node; msg rows are contiguous per node (CSR).
// ---------------------------------------------------------------------------
__global__ __launch_bounds__(256)
void agg_ln_kernel(const float* __restrict__ x, const float* __restrict__ msg,
                   const int* __restrict__ start,
                   const float* __restrict__ g, const float* __restrict__ b,
                   float* __restrict__ out0, int N)
{
    int lane = threadIdx.x & 63;
    int row  = blockIdx.x * 4 + (threadIdx.x >> 6);
    if (row >= N) return;
    int s0 = start[row], s1 = start[row + 1];
    float4 h = reinterpret_cast<const float4*>(x)[row * 64 + lane];
    for (int s = s0; s < s1; ++s) {
        float4 m = reinterpret_cast<const float4*>(msg)[(size_t)s * 64 + lane];
        h.x += m.x; h.y += m.y; h.z += m.z; h.w += m.w;
    }
    float su  = h.x + h.y + h.z + h.w;
    float s2 = h.x * h.x + h.y * h.y + h.z * h.z + h.w * h.w;
    #pragma unroll
    for (int off = 32; off > 0; off >>= 1) {
        su += __shfl_xor(su, off, 64);
        s2 += __shfl_xor(s2, off, 64);
    }
    float mu  = su * (1.0f / 256.0f);
    float var = s2 * (1.0f / 256.0f) - mu * mu;
    float inv = rsqrtf(var + F_EPS_LN);
    float4 gv = reinterpret_cast<const float4*>(g)[lane];
    float4 bv = reinterpret_cast<const float4*>(b)[lane];
    float4 o;
    o.x = (h.x - mu) * inv * gv.x + bv.x;
    o.y = (h.y - mu) * inv * gv.y + bv.y;
    o.z = (h.z - mu) * inv * gv.z + bv.z;
    o.w = (h.w - mu) * inv * gv.w + bv.w;
    reinterpret_cast<float4*>(out0)[row * 64 + lane] = o;
}

// ---------------------------------------------------------------------------
// LayerNorm in-place (fallback path): d_out = LN(x + d_out) * g + b
// ---------------------------------------------------------------------------
__global__ __launch_bounds__(256)
void ln_kernel(const float* __restrict__ x, const float* __restrict__ agg,
               const float* __restrict__ g, const float* __restrict__ b,
               float* __restrict__ out0, int N)
{
    int lane = threadIdx.x & 63;
    int row  = blockIdx.x * 4 + (threadIdx.x >> 6);
    if (row >= N) return;
    float4 hx = reinterpret_cast<const float4*>(x)[row * 64 + lane];
    float4 ha = reinterpret_cast<const float4*>(agg)[row * 64 + lane];
    float4 h  = make_float4(hx.x + ha.x, hx.y + ha.y, hx.z + ha.z, hx.w + ha.w);
    float s  = h.x + h.y + h.z + h.w;
    float s2 = h.x * h.x + h.y * h.y + h.z * h.z + h.w * h.w;
    #pragma unroll
    for (int off = 32; off > 0; off >>= 1) {
        s  += __shfl_xor(s,  off, 64);
        s2 += __shfl_xor(s2, off, 64);
    }
    float mu  = s * (1.0f / 256.0f);
    float var = s2 * (1.0f / 256.0f) - mu * mu;
    float inv = rsqrtf(var + F_EPS_LN);
    float4 gv = reinterpret_cast<const float4*>(g)[lane];
    float4 bv = reinterpret_cast<const float4*>(b)[lane];
    float4 o;
    o.x = (h.x - mu) * inv * gv.x + bv.x;
    o.y = (h.y - mu) * inv * gv.y + bv.y;
    o.z = (h.z - mu) * inv * gv.z + bv.z;
    o.w = (h.w - mu) * inv * gv.w + bv.w;
    reinterpret_cast<float4*>(out0)[row * 64 + lane] = o;
}

// ---------------------------------------------------------------------------
extern "C" void kernel_launch(void* const* d_in, const int* in_sizes, int n_in,
                              void* d_out, int out_size, void* d_ws, size_t ws_size,
                              hipStream_t stream)
{
    const float* x       = (const float*)d_in[0];
    const int*   eidx    = (const int*)  d_in[1];
    const float* dist    = (const float*)d_in[2];
    const float* centers = (const float*)d_in[3];
    const float* widths  = (const float*)d_in[4];
    const float* rbf_w1  = (const float*)d_in[5];
    const float* rbf_b1  = (const float*)d_in[6];
    const float* rbf_w2  = (const float*)d_in[7];
    const float* rbf_b2  = (const float*)d_in[8];
    const float* filt_w1 = (const float*)d_in[9];
    const float* filt_b1 = (const float*)d_in[10];
    const float* filt_w2 = (const float*)d_in[11];
    const float* filt_b2 = (const float*)d_in[12];
    const float* filt_w3 = (const float*)d_in[13];
    const float* filt_b3 = (const float*)d_in[14];
    const float* node_w  = (const float*)d_in[15];
    const float* node_b  = (const float*)d_in[16];
    const float* ln_g    = (const float*)d_in[17];
    const float* ln_b    = (const float*)d_in[18];
    const float* gate_w  = (const float*)d_in[19];
    const float* gate_b  = (const float*)d_in[20];

    const int N = in_sizes[0] / 256;
    const int E = in_sizes[2];

    // ---- ws layout (byte-offset allocator)
    char* wsb = (char*)d_ws;
    size_t off = 0;
    auto alloc = [&](size_t bytes, size_t align) -> char* {
        off = (off + align - 1) & ~(align - 1);
        char* p = wsb + off;
        off += bytes;
        return p;
    };
    ushort_t* y_bf  = (ushort_t*)alloc((size_t)N * 256 * 2, 16);
    ushort_t* wt1   = (ushort_t*)alloc(64 * 64 * 2, 16);
    ushort_t* wcomb = (ushort_t*)alloc(256 * 64 * 2, 16);
    ushort_t* wf2   = (ushort_t*)alloc(256 * 256 * 2, 16);
    ushort_t* wf3   = (ushort_t*)alloc(256 * 256 * 2, 16);
    float*    bcomb = (float*)   alloc(256 * 4, 16);
    int*      cnt   = (int*)     alloc((size_t)N * 4, 16);
    int*      start = (int*)     alloc(((size_t)N + 1) * 4, 16);
    int*      cursor= (int*)     alloc((size_t)N * 4, 16);
    int*      slot  = (int*)     alloc((size_t)E * 4, 16);
    float*    msg   = (float*)   alloc((size_t)E * 256 * 4, 1024);
    const bool two_phase = (off <= ws_size);

    dim3 b256(256);

    // weights prep (independent)
    cvt_transpose_kernel<<<dim3((64 * 64 + 255) / 256),   b256, 0, stream>>>(rbf_w1,  wt1, 64, 64, 6);
    combine_w_kernel<<<dim3(64), b256, 0, stream>>>(rbf_w2, filt_w1, wcomb);
    combine_b_kernel<<<dim3(1), b256, 0, stream>>>(rbf_b2, filt_w1, filt_b1, bcomb);
    cvt_transpose_kernel<<<dim3((256 * 256 + 255) / 256), b256, 0, stream>>>(filt_w2, wf2, 256, 256, 8);
    cvt_transpose_kernel<<<dim3((256 * 256 + 255) / 256), b256, 0, stream>>>(filt_w3, wf3, 256, 256, 8);

    gemm256_bf16_kernel<<<dim3((N + 63) / 64), b256, 0, stream>>>(x, node_w, node_b, y_bf, N);

    if (two_phase) {
        hipMemsetAsync(cnt, 0, (size_t)N * 4, stream);
        count_kernel<<<dim3((E + 255) / 256), b256, 0, stream>>>(eidx, cnt, E);
        scan_kernel<<<dim3(1), 1024, 0, stream>>>(cnt, start, cursor, N);
        scatter_kernel<<<dim3((E + 255) / 256), b256, 0, stream>>>(eidx, cursor, slot, E);

        edge_mfma_kernel<1><<<dim3((E + 31) / 32), b256, 0, stream>>>(
            dist, eidx, centers, widths,
            wt1, rbf_b1, wcomb, bcomb,
            wf2, filt_b2, wf3, filt_b3,
            y_bf, slot, msg, E);

        agg_ln_kernel<<<dim3((N + 3) / 4), b256, 0, stream>>>(x, msg, start, ln_g, ln_b, (float*)d_out, N);
    } else {
        hipMemsetAsync(d_out, 0, (size_t)out_size * sizeof(float), stream);
        edge_mfma_kernel<0><<<dim3((E + 31) / 32), b256, 0, stream>>>(
            dist, eidx, centers, widths,
            wt1, rbf_b1, wcomb, bcomb,
            wf2, filt_b2, wf3, filt_b3,
            y_bf, slot, (float*)d_out, E);
        ln_kernel<<<dim3((N + 3) / 4), b256, 0, stream>>>(x, (float*)d_out, ln_g, ln_b, (float*)d_out, N);
    }

    gate_gemm_kernel<<<dim3((N + 63) / 64), b256, 0, stream>>>((float*)d_out, gate_w, gate_b, (float*)d_out, N);
}

// Round 6
// 822.758 us; speedup vs baseline: 3.2123x; 1.0001x over previous
//
#include <hip/hip_runtime.h>
#include <hip/hip_bf16.h>
#include <math.h>

typedef __attribute__((ext_vector_type(8))) short bf16x8;
typedef __attribute__((ext_vector_type(4))) float f32x4;
typedef unsigned short ushort_t;

constexpr float F_CUTOFF = 10.0f;
constexpr float F_EPS_W  = 1e-5f;
constexpr float F_EPS_LN = 1e-5f;
constexpr float F_PI     = 3.14159265358979323846f;

__device__ __forceinline__ float silu_f(float v)   { return v / (1.0f + __expf(-v)); }
__device__ __forceinline__ float sigmoid_f(float v){ return 1.0f / (1.0f + __expf(-v)); }

__device__ __forceinline__ ushort_t f2bf(float f) {
    union { __hip_bfloat16 h; ushort_t u; } v; v.h = __float2bfloat16(f); return v.u;
}
__device__ __forceinline__ float bf2f(ushort_t u) {
    union { unsigned u; float f; } v; v.u = ((unsigned)u) << 16; return v.f;
}

__device__ __forceinline__ float f4c(const float4& v, int q) {
    return q == 0 ? v.x : q == 1 ? v.y : q == 2 ? v.z : v.w;
}

// ---------------------------------------------------------------------------
// CSR build
// ---------------------------------------------------------------------------
__global__ void count_kernel(const int* __restrict__ eidx, int* __restrict__ cnt, int E)
{
    int e = blockIdx.x * 256 + threadIdx.x;
    if (e < E) atomicAdd(&cnt[eidx[e]], 1);
}

__global__ __launch_bounds__(1024)
void scan_kernel(int* __restrict__ cnt /* in: counts, out: cursor */,
                 int* __restrict__ start, int N)
{
    __shared__ int part[1024];
    const int tid = threadIdx.x;
    const int C = (N + 1023) >> 10;
    const int base = tid * C;
    int s = 0;
    for (int i = 0; i < C; ++i) {
        int idx = base + i;
        if (idx < N) s += cnt[idx];
    }
    part[tid] = s;
    __syncthreads();
    for (int off = 1; off < 1024; off <<= 1) {
        int v = (tid >= off) ? part[tid - off] : 0;
        __syncthreads();
        part[tid] += v;
        __syncthreads();
    }
    int run = part[tid] - s;   // exclusive prefix
    for (int i = 0; i < C; ++i) {
        int idx = base + i;
        if (idx < N) {
            int c = cnt[idx];
            start[idx] = run;
            cnt[idx]   = run;   // cursor
            run += c;
        }
    }
    if (tid == 1023) start[N] = part[1023];
}

__global__ void scatter_kernel(const int* __restrict__ eidx, int* __restrict__ cursor,
                               int* __restrict__ slot, int* __restrict__ colos, int E)
{
    int e = blockIdx.x * 256 + threadIdx.x;
    if (e < E) {
        int s = atomicAdd(&cursor[eidx[e]], 1);
        slot[e] = s;
        colos[s] = eidx[E + e];
    }
}

// ---------------------------------------------------------------------------
// Weight convert+transpose: fp32 [K][N] -> bf16 [N][K].
// ---------------------------------------------------------------------------
__global__ void cvt_transpose_kernel(const float* __restrict__ in, ushort_t* __restrict__ out,
                                     int K, int N, int logK)
{
    int idx = blockIdx.x * 256 + threadIdx.x;
    if (idx >= K * N) return;
    int n = idx >> logK;
    int k = idx & (K - 1);
    out[idx] = f2bf(in[k * N + n]);
}

// wcomb[c][j] = sum_n rbf_w2[j][n] * filt_w1[n][c]  -> bf16 [256][64]
__global__ void combine_w_kernel(const float* __restrict__ w2, const float* __restrict__ fw1,
                                 ushort_t* __restrict__ out)
{
    int idx = blockIdx.x * 256 + threadIdx.x;
    int c = idx >> 6, j = idx & 63;
    float s = 0.f;
    #pragma unroll 8
    for (int n = 0; n < 64; ++n) s += w2[j * 64 + n] * fw1[n * 256 + c];
    out[idx] = f2bf(s);
}

__global__ void combine_b_kernel(const float* __restrict__ b2, const float* __restrict__ fw1,
                                 const float* __restrict__ fb1, float* __restrict__ out)
{
    int c = threadIdx.x;
    float s = fb1[c];
    #pragma unroll 8
    for (int n = 0; n < 64; ++n) s += b2[n] * fw1[n * 256 + c];
    out[c] = s;
}

// ---------------------------------------------------------------------------
// y = x @ node_w + node_b, output bf16.
// ---------------------------------------------------------------------------
__global__ __launch_bounds__(256)
void gemm256_bf16_kernel(const float* __restrict__ A, const float* __restrict__ Wm,
                         const float* __restrict__ bias, ushort_t* __restrict__ out, int M)
{
    __shared__ float4 As4[64][64];
    const int t = threadIdx.x;
    const int row0 = blockIdx.x * 64;

    #pragma unroll
    for (int i = 0; i < 16; ++i) {
        int flat = t + i * 256;
        int r = flat >> 6, k4 = flat & 63;
        int row = row0 + r;
        float4 v = make_float4(0.f, 0.f, 0.f, 0.f);
        if (row < M) v = reinterpret_cast<const float4*>(A)[row * 64 + k4];
        As4[r][k4] = v;
    }
    __syncthreads();

    const int jt  = t & 31;
    const int et  = t >> 5;
    const int j04 = jt * 2;
    const int r0  = et * 8;

    float acc[8][8];
    #pragma unroll
    for (int r = 0; r < 8; ++r)
        #pragma unroll
        for (int c = 0; c < 8; ++c) acc[r][c] = 0.f;

    for (int k4 = 0; k4 < 64; ++k4) {
        float4 a4[8];
        #pragma unroll
        for (int r = 0; r < 8; ++r) a4[r] = As4[r0 + r][k4];
        #pragma unroll
        for (int q = 0; q < 4; ++q) {
            const int k = k4 * 4 + q;
            float4 b0 = reinterpret_cast<const float4*>(Wm)[k * 64 + j04];
            float4 b1 = reinterpret_cast<const float4*>(Wm)[k * 64 + j04 + 1];
            float bb[8] = {b0.x, b0.y, b0.z, b0.w, b1.x, b1.y, b1.z, b1.w};
            #pragma unroll
            for (int r = 0; r < 8; ++r) {
                float av = f4c(a4[r], q);
                #pragma unroll
                for (int c = 0; c < 8; ++c) acc[r][c] = fmaf(av, bb[c], acc[r][c]);
            }
        }
    }

    float4 bv0 = reinterpret_cast<const float4*>(bias)[j04];
    float4 bv1 = reinterpret_cast<const float4*>(bias)[j04 + 1];
    float bb[8] = {bv0.x, bv0.y, bv0.z, bv0.w, bv1.x, bv1.y, bv1.z, bv1.w};

    #pragma unroll
    for (int r = 0; r < 8; ++r) {
        int row = row0 + r0 + r;
        if (row >= M) continue;
        ushort_t o8[8];
        #pragma unroll
        for (int c = 0; c < 8; ++c) o8[c] = f2bf(acc[r][c] + bb[c]);
        *reinterpret_cast<uint4*>(out + (size_t)row * 256 + jt * 8) = *reinterpret_cast<uint4*>(o8);
    }
}

// ---------------------------------------------------------------------------
// Gate GEMM (fp32): out = A * sigmoid(A@W + b), in-place safe per 64-row block.
// ---------------------------------------------------------------------------
__global__ __launch_bounds__(256)
void gate_gemm_kernel(const float* __restrict__ A, const float* __restrict__ Wm,
                      const float* __restrict__ bias, float* __restrict__ out, int M)
{
    __shared__ float4 As4[64][64];
    const int t = threadIdx.x;
    const int row0 = blockIdx.x * 64;

    #pragma unroll
    for (int i = 0; i < 16; ++i) {
        int flat = t + i * 256;
        int r = flat >> 6, k4 = flat & 63;
        int row = row0 + r;
        float4 v = make_float4(0.f, 0.f, 0.f, 0.f);
        if (row < M) v = reinterpret_cast<const float4*>(A)[row * 64 + k4];
        As4[r][k4] = v;
    }
    __syncthreads();

    const int jt  = t & 31;
    const int et  = t >> 5;
    const int j04 = jt * 2;
    const int r0  = et * 8;

    float acc[8][8];
    #pragma unroll
    for (int r = 0; r < 8; ++r)
        #pragma unroll
        for (int c = 0; c < 8; ++c) acc[r][c] = 0.f;

    for (int k4 = 0; k4 < 64; ++k4) {
        float4 a4[8];
        #pragma unroll
        for (int r = 0; r < 8; ++r) a4[r] = As4[r0 + r][k4];
        #pragma unroll
        for (int q = 0; q < 4; ++q) {
            const int k = k4 * 4 + q;
            float4 b0 = reinterpret_cast<const float4*>(Wm)[k * 64 + j04];
            float4 b1 = reinterpret_cast<const float4*>(Wm)[k * 64 + j04 + 1];
            float bb[8] = {b0.x, b0.y, b0.z, b0.w, b1.x, b1.y, b1.z, b1.w};
            #pragma unroll
            for (int r = 0; r < 8; ++r) {
                float av = f4c(a4[r], q);
                #pragma unroll
                for (int c = 0; c < 8; ++c) acc[r][c] = fmaf(av, bb[c], acc[r][c]);
            }
        }
    }

    float4 bv0 = reinterpret_cast<const float4*>(bias)[j04];
    float4 bv1 = reinterpret_cast<const float4*>(bias)[j04 + 1];
    float bb[8] = {bv0.x, bv0.y, bv0.z, bv0.w, bv1.x, bv1.y, bv1.z, bv1.w};

    #pragma unroll
    for (int r = 0; r < 8; ++r) {
        int row = row0 + r0 + r;
        if (row >= M) continue;
        float4 a0 = As4[r0 + r][j04];
        float4 a1 = As4[r0 + r][j04 + 1];
        float aa[8] = {a0.x, a0.y, a0.z, a0.w, a1.x, a1.y, a1.z, a1.w};
        float o[8];
        #pragma unroll
        for (int c = 0; c < 8; ++c) o[c] = aa[c] * sigmoid_f(acc[r][c] + bb[c]);
        reinterpret_cast<float4*>(out)[row * 64 + j04]     = make_float4(o[0], o[1], o[2], o[3]);
        reinterpret_cast<float4*>(out)[row * 64 + j04 + 1] = make_float4(o[4], o[5], o[6], o[7]);
    }
}

// ---------------------------------------------------------------------------
// mlp_stage (proven): 32 edges, 4 waves (1m x 4n), LDS 512B-row swizzled.
// ---------------------------------------------------------------------------
template<int KS, int NT, bool SILU>
__device__ __forceinline__ void mlp_stage(const unsigned char* in, unsigned char* out,
                                          const ushort_t* __restrict__ Wt,
                                          const float* __restrict__ bias,
                                          int wn, int g, int q)
{
    constexpr int K = KS * 32;
    f32x4 acc[2][NT];
    #pragma unroll
    for (int mt = 0; mt < 2; ++mt)
        #pragma unroll
        for (int nt = 0; nt < NT; ++nt) acc[mt][nt] = (f32x4){0.f, 0.f, 0.f, 0.f};

    #pragma unroll
    for (int kk = 0; kk < KS; ++kk) {
        bf16x8 b[NT];
        #pragma unroll
        for (int nt = 0; nt < NT; ++nt) {
            int n = (wn * NT + nt) * 16 + q;
            b[nt] = *reinterpret_cast<const bf16x8*>(Wt + n * K + kk * 32 + g * 8);
        }
        bf16x8 a[2];
        #pragma unroll
        for (int mt = 0; mt < 2; ++mt) {
            int m = mt * 16 + q;
            int unit = (4 * kk + g) ^ (m & 7);
            a[mt] = *reinterpret_cast<const bf16x8*>(in + m * 512 + unit * 16);
        }
        #pragma unroll
        for (int mt = 0; mt < 2; ++mt)
            #pragma unroll
            for (int nt = 0; nt < NT; ++nt)
                acc[mt][nt] = __builtin_amdgcn_mfma_f32_16x16x32_bf16(a[mt], b[nt], acc[mt][nt], 0, 0, 0);
    }

    const bool evenq = (q & 1) == 0;
    #pragma unroll
    for (int nt = 0; nt < NT; ++nt) {
        int n0  = (wn * NT + nt) * 16 + q;
        int n_e = n0 & ~1;
        float2 bv = *reinterpret_cast<const float2*>(bias + n_e);
        #pragma unroll
        for (int mt = 0; mt < 2; ++mt) {
            float v[4], p[4];
            #pragma unroll
            for (int r = 0; r < 4; ++r) { v[r] = acc[mt][nt][r]; p[r] = __shfl_xor(v[r], 1, 64); }
            #pragma unroll
            for (int rr = 0; rr < 2; ++rr) {
                int r = evenq ? rr : (2 + rr);
                float lo = (evenq ? v[r] : p[r]) + bv.x;
                float hi = (evenq ? p[r] : v[r]) + bv.y;
                if (SILU) { lo = silu_f(lo); hi = silu_f(hi); }
                int m = mt * 16 + 4 * g + r;
                unsigned u = (unsigned)f2bf(lo) | ((unsigned)f2bf(hi) << 16);
                int byte = m * 512 + (((n_e >> 3) ^ (m & 7)) << 4) + ((n_e & 7) * 2);
                *reinterpret_cast<unsigned*>(out + byte) = u;
            }
        }
    }
}

// ---------------------------------------------------------------------------
// Stage A: RBF -> t1 -> f1, write f1 bf16 [E,256] to global.
// ---------------------------------------------------------------------------
__global__ __launch_bounds__(256, 4)
void rbf_f1_kernel(const float* __restrict__ dist,
                   const float* __restrict__ centers, const float* __restrict__ widths,
                   const ushort_t* __restrict__ wt_rbf1, const float* __restrict__ rbf_b1,
                   const ushort_t* __restrict__ wt_comb, const float* __restrict__ b_comb,
                   ushort_t* __restrict__ f1, int E)
{
    __shared__ __align__(16) unsigned char bufA[16384];
    __shared__ __align__(16) unsigned char bufB[16384];

    const int t  = threadIdx.x;
    const int e0 = blockIdx.x * 32;
    const int wn   = t >> 6;
    const int lane = t & 63;
    const int g = lane >> 4, q = lane & 15;

    const int e_own  = t >> 3;
    const int chunk  = t & 7;
    const int ge_own = e0 + e_own;

    // S0: RBF features r[32][64] -> bufA (swizzled)
    {
        float d = (ge_own < E) ? dist[ge_own] : F_CUTOFF;
        float env = (d < F_CUTOFF) ? 0.5f * (__cosf(d * (F_PI / F_CUTOFF)) + 1.0f) : 0.0f;
        unsigned char* rowp = bufA + e_own * 512;
        int k0 = chunk * 8;
        #pragma unroll
        for (int i = 0; i < 4; ++i) {
            int n = k0 + 2 * i;
            float c0 = centers[n],     w0 = fabsf(widths[n]) + F_EPS_W;
            float c1 = centers[n + 1], w1 = fabsf(widths[n + 1]) + F_EPS_W;
            float z0 = (d - c0) / w0, z1 = (d - c1) / w1;
            float r0 = env * __expf(-0.5f * z0 * z0);
            float r1 = env * __expf(-0.5f * z1 * z1);
            unsigned u = (unsigned)f2bf(r0) | ((unsigned)f2bf(r1) << 16);
            int byte = (((n >> 3) ^ (e_own & 7)) << 4) + ((n & 7) * 2);
            *reinterpret_cast<unsigned*>(rowp + byte) = u;
        }
    }
    __syncthreads();

    mlp_stage<2, 1, true>(bufA, bufB, wt_rbf1, rbf_b1, wn, g, q);  // t1
    __syncthreads();
    mlp_stage<2, 4, true>(bufB, bufA, wt_comb, b_comb, wn, g, q);  // f1
    __syncthreads();

    // store f1 (unswizzle): thread covers chunks chunk + 8i of its edge
    if (ge_own < E) {
        #pragma unroll
        for (int i = 0; i < 4; ++i) {
            int c = chunk + i * 8;     // 0..31 chunk of 8 cols
            int u = (c ^ (e_own & 7)) | (c & 24);   // XOR affects low 3 bits only
            // note: c^(e&7) already keeps high bits; recompute cleanly:
            u = (c & 24) | ((c ^ (e_own & 7)) & 7);
            uint4 v = *reinterpret_cast<const uint4*>(bufA + e_own * 512 + u * 16);
            *reinterpret_cast<uint4*>(f1 + (size_t)ge_own * 256 + c * 8) = v;
        }
    }
}

// ---------------------------------------------------------------------------
// Dense GEMM stage: C[M,256] = act(A[M,256] @ W + bias), bf16 in/out, MFMA.
// BM=64, BN=256, BK=64 double-buffered in LDS. 256 threads, 4 waves (n-split).
// EPI=0: silu, store at row m.  EPI=1: no act, store at row slot[m].
// ---------------------------------------------------------------------------
template<int EPI>
__global__ __launch_bounds__(256, 3)
void gemm_stage_kernel(const ushort_t* __restrict__ A, const ushort_t* __restrict__ Wt,
                       const float* __restrict__ bias, ushort_t* __restrict__ out,
                       const int* __restrict__ slot, int M)
{
    __shared__ __align__(16) unsigned char sbuf[2][8192];   // 64 rows x 128B
    __shared__ int slot_s[64];

    const int t  = threadIdx.x;
    const int m0 = blockIdx.x * 64;
    const int wn   = t >> 6;
    const int lane = t & 63;
    const int g = lane >> 4, q = lane & 15;

    if (EPI == 1 && t < 64) {
        int gm = m0 + t;
        slot_s[t] = (gm < M) ? slot[gm] : 0;
    }

    // staging: 512 slots of 16B; thread covers s = t and t+256.
    // slot s -> (r = s>>3, u = s&7); stored source col-chunk = u ^ (r&7)
    const int s0r = t >> 3,        s0u = t & 7;
    const int s1r = (t + 256) >> 3, s1u = t & 7;
    const ushort_t* src0base = A + (size_t)((m0 + s0r < M) ? (m0 + s0r) : (M - 1)) * 256 + ((s0u ^ (s0r & 7)) * 8);
    const ushort_t* src1base = A + (size_t)((m0 + s1r < M) ? (m0 + s1r) : (M - 1)) * 256 + ((s1u ^ (s1r & 7)) * 8);

    // prologue: kt = 0
    uint4 p0 = *reinterpret_cast<const uint4*>(src0base);
    uint4 p1 = *reinterpret_cast<const uint4*>(src1base);
    *reinterpret_cast<uint4*>(&sbuf[0][t * 16])         = p0;
    *reinterpret_cast<uint4*>(&sbuf[0][(t + 256) * 16]) = p1;
    __syncthreads();

    f32x4 acc[4][4];
    #pragma unroll
    for (int mt = 0; mt < 4; ++mt)
        #pragma unroll
        for (int nt = 0; nt < 4; ++nt) acc[mt][nt] = (f32x4){0.f, 0.f, 0.f, 0.f};

    for (int kt = 0; kt < 4; ++kt) {
        const int cur = kt & 1;
        uint4 nx0, nx1;
        if (kt < 3) {
            nx0 = *reinterpret_cast<const uint4*>(src0base + (kt + 1) * 64);
            nx1 = *reinterpret_cast<const uint4*>(src1base + (kt + 1) * 64);
        }
        #pragma unroll
        for (int ks = 0; ks < 2; ++ks) {
            bf16x8 b[4];
            #pragma unroll
            for (int nt = 0; nt < 4; ++nt) {
                int n = wn * 64 + nt * 16 + q;
                b[nt] = *reinterpret_cast<const bf16x8*>(Wt + (size_t)n * 256 + kt * 64 + ks * 32 + g * 8);
            }
            bf16x8 a[4];
            #pragma unroll
            for (int mt = 0; mt < 4; ++mt) {
                int r = mt * 16 + q;
                int u = (ks * 4 + g) ^ (r & 7);
                a[mt] = *reinterpret_cast<const bf16x8*>(&sbuf[cur][r * 128 + u * 16]);
            }
            #pragma unroll
            for (int mt = 0; mt < 4; ++mt)
                #pragma unroll
                for (int nt = 0; nt < 4; ++nt)
                    acc[mt][nt] = __builtin_amdgcn_mfma_f32_16x16x32_bf16(a[mt], b[nt], acc[mt][nt], 0, 0, 0);
        }
        __syncthreads();
        if (kt < 3) {
            *reinterpret_cast<uint4*>(&sbuf[cur ^ 1][t * 16])         = nx0;
            *reinterpret_cast<uint4*>(&sbuf[cur ^ 1][(t + 256) * 16]) = nx1;
            __syncthreads();
        }
    }

    // epilogue: pair-pack via shfl_xor(1), u32 stores
    const bool evenq = (q & 1) == 0;
    #pragma unroll
    for (int nt = 0; nt < 4; ++nt) {
        int n0  = wn * 64 + nt * 16 + q;
        int n_e = n0 & ~1;
        float2 bv = *reinterpret_cast<const float2*>(bias + n_e);
        #pragma unroll
        for (int mt = 0; mt < 4; ++mt) {
            float v[4], p[4];
            #pragma unroll
            for (int r = 0; r < 4; ++r) { v[r] = acc[mt][nt][r]; p[r] = __shfl_xor(v[r], 1, 64); }
            #pragma unroll
            for (int rr = 0; rr < 2; ++rr) {
                int r = evenq ? rr : (2 + rr);
                float lo = (evenq ? v[r] : p[r]) + bv.x;
                float hi = (evenq ? p[r] : v[r]) + bv.y;
                if (EPI == 0) { lo = silu_f(lo); hi = silu_f(hi); }
                int mloc = mt * 16 + 4 * g + r;
                int grow = m0 + mloc;
                if (grow < M) {
                    int drow = (EPI == 1) ? slot_s[mloc] : grow;
                    unsigned u = (unsigned)f2bf(lo) | ((unsigned)f2bf(hi) << 16);
                    *reinterpret_cast<unsigned*>(out + (size_t)drow * 256 + n_e) = u;
                }
            }
        }
    }
}

// ---------------------------------------------------------------------------
// agg + residual + LN: out0 = LN(x + sum_s Wf[s]*y[col(s)]) * g + b
// One wave per node; Wf rows contiguous per node (CSR slot order).
// ---------------------------------------------------------------------------
__global__ __launch_bounds__(256)
void agg_ln2_kernel(const float* __restrict__ x, const ushort_t* __restrict__ Wf,
                    const int* __restrict__ start, const int* __restrict__ colos,
                    const ushort_t* __restrict__ y,
                    const float* __restrict__ g, const float* __restrict__ b,
                    float* __restrict__ out0, int N)
{
    int lane = threadIdx.x & 63;
    int row  = blockIdx.x * 4 + (threadIdx.x >> 6);
    if (row >= N) return;
    int s0 = start[row], s1 = start[row + 1];
    float4 hx = reinterpret_cast<const float4*>(x)[row * 64 + lane];
    float hh[4] = {hx.x, hx.y, hx.z, hx.w};
    for (int s = s0; s < s1; ++s) {
        uint2 wv = *reinterpret_cast<const uint2*>(Wf + (size_t)s * 256 + lane * 4);
        int c = colos[s];
        uint2 yv = *reinterpret_cast<const uint2*>(y + (size_t)c * 256 + lane * 4);
        hh[0] += bf2f((ushort_t)(wv.x & 0xffff)) * bf2f((ushort_t)(yv.x & 0xffff));
        hh[1] += bf2f((ushort_t)(wv.x >> 16))    * bf2f((ushort_t)(yv.x >> 16));
        hh[2] += bf2f((ushort_t)(wv.y & 0xffff)) * bf2f((ushort_t)(yv.y & 0xffff));
        hh[3] += bf2f((ushort_t)(wv.y >> 16))    * bf2f((ushort_t)(yv.y >> 16));
    }
    float su = hh[0] + hh[1] + hh[2] + hh[3];
    float s2 = hh[0]*hh[0] + hh[1]*hh[1] + hh[2]*hh[2] + hh[3]*hh[3];
    #pragma unroll
    for (int off = 32; off > 0; off >>= 1) {
        su += __shfl_xor(su, off, 64);
        s2 += __shfl_xor(s2, off, 64);
    }
    float mu  = su * (1.0f / 256.0f);
    float var = s2 * (1.0f / 256.0f) - mu * mu;
    float inv = rsqrtf(var + F_EPS_LN);
    float4 gv = reinterpret_cast<const float4*>(g)[lane];
    float4 bv = reinterpret_cast<const float4*>(b)[lane];
    float4 o;
    o.x = (hh[0] - mu) * inv * gv.x + bv.x;
    o.y = (hh[1] - mu) * inv * gv.y + bv.y;
    o.z = (hh[2] - mu) * inv * gv.z + bv.z;
    o.w = (hh[3] - mu) * inv * gv.w + bv.w;
    reinterpret_cast<float4*>(out0)[row * 64 + lane] = o;
}

// ---------------------------------------------------------------------------
// Fallback (ws too small): fused atomic-scatter edge kernel + LN (R5 proven).
// ---------------------------------------------------------------------------
__global__ __launch_bounds__(256, 4)
void edge_atomic_kernel(const float* __restrict__ dist, const int* __restrict__ eidx,
                        const float* __restrict__ centers, const float* __restrict__ widths,
                        const ushort_t* __restrict__ wt_rbf1, const float* __restrict__ rbf_b1,
                        const ushort_t* __restrict__ wt_comb, const float* __restrict__ b_comb,
                        const ushort_t* __restrict__ wt_f2, const float* __restrict__ filt_b2,
                        const ushort_t* __restrict__ wt_f3, const float* __restrict__ filt_b3,
                        const ushort_t* __restrict__ y, float* __restrict__ agg, int E)
{
    __shared__ __align__(16) unsigned char bufA[16384];
    __shared__ __align__(16) unsigned char bufB[16384];
    __shared__ int rs_s[32];

    const int t  = threadIdx.x;
    const int e0 = blockIdx.x * 32;
    const int wn   = t >> 6;
    const int lane = t & 63;
    const int g = lane >> 4, q = lane & 15;

    if (t < 32) {
        int ge = e0 + t;
        rs_s[t] = (ge < E) ? eidx[ge] : 0;
    }

    const int e_own  = t >> 3;
    const int chunk  = t & 7;
    const int ge_own = e0 + e_own;
    const int col_own = (ge_own < E) ? eidx[E + ge_own] : 0;
    uint4 yv[4];
    #pragma unroll
    for (int i = 0; i < 4; ++i)
        yv[i] = *reinterpret_cast<const uint4*>(y + (size_t)col_own * 256 + (i * 8 + chunk) * 8);

    {
        float d = (ge_own < E) ? dist[ge_own] : F_CUTOFF;
        float env = (d < F_CUTOFF) ? 0.5f * (__cosf(d * (F_PI / F_CUTOFF)) + 1.0f) : 0.0f;
        unsigned char* rowp = bufA + e_own * 512;
        int k0 = chunk * 8;
        #pragma unroll
        for (int i = 0; i < 4; ++i) {
            int n = k0 + 2 * i;
            float c0 = centers[n],     w0 = fabsf(widths[n]) + F_EPS_W;
            float c1 = centers[n + 1], w1 = fabsf(widths[n + 1]) + F_EPS_W;
            float z0 = (d - c0) / w0, z1 = (d - c1) / w1;
            float r0 = env * __expf(-0.5f * z0 * z0);
            float r1 = env * __expf(-0.5f * z1 * z1);
            unsigned u = (unsigned)f2bf(r0) | ((unsigned)f2bf(r1) << 16);
            int byte = (((n >> 3) ^ (e_own & 7)) << 4) + ((n & 7) * 2);
            *reinterpret_cast<unsigned*>(rowp + byte) = u;
        }
    }
    __syncthreads();

    mlp_stage<2, 1, true>(bufA, bufB, wt_rbf1, rbf_b1, wn, g, q);
    __syncthreads();
    mlp_stage<2, 4, true>(bufB, bufA, wt_comb, b_comb, wn, g, q);
    __syncthreads();
    mlp_stage<8, 4, true>(bufA, bufB, wt_f2, filt_b2, wn, g, q);
    __syncthreads();

    #pragma unroll
    for (int i = 0; i < 4; ++i)
        *reinterpret_cast<uint4*>(bufA + e_own * 512 + (i * 8 + chunk) * 16) = yv[i];
    __syncthreads();

    {
        f32x4 acc[2][4];
        #pragma unroll
        for (int mt = 0; mt < 2; ++mt)
            #pragma unroll
            for (int nt = 0; nt < 4; ++nt) acc[mt][nt] = (f32x4){0.f, 0.f, 0.f, 0.f};

        #pragma unroll
        for (int kk = 0; kk < 8; ++kk) {
            bf16x8 b[4];
            #pragma unroll
            for (int nt = 0; nt < 4; ++nt) {
                int n = (wn * 4 + nt) * 16 + q;
                b[nt] = *reinterpret_cast<const bf16x8*>(wt_f3 + n * 256 + kk * 32 + g * 8);
            }
            bf16x8 a[2];
            #pragma unroll
            for (int mt = 0; mt < 2; ++mt) {
                int m = mt * 16 + q;
                int unit = (4 * kk + g) ^ (m & 7);
                a[mt] = *reinterpret_cast<const bf16x8*>(bufB + m * 512 + unit * 16);
            }
            #pragma unroll
            for (int mt = 0; mt < 2; ++mt)
                #pragma unroll
                for (int nt = 0; nt < 4; ++nt)
                    acc[mt][nt] = __builtin_amdgcn_mfma_f32_16x16x32_bf16(a[mt], b[nt], acc[mt][nt], 0, 0, 0);
        }

        float bn[4];
        int   nn[4];
        #pragma unroll
        for (int nt = 0; nt < 4; ++nt) { nn[nt] = (wn * 4 + nt) * 16 + q; bn[nt] = filt_b3[nn[nt]]; }

        #pragma unroll
        for (int mt = 0; mt < 2; ++mt) {
            #pragma unroll
            for (int r = 0; r < 4; ++r) {
                int m  = mt * 16 + 4 * g + r;
                int ge = e0 + m;
                if (ge < E) {
                    const unsigned char* yrow = bufA + m * 512;
                    float* arow = agg + (size_t)rs_s[m] * 256;
                    #pragma unroll
                    for (int nt = 0; nt < 4; ++nt) {
                        float wv = acc[mt][nt][r] + bn[nt];
                        float yvv = bf2f(*reinterpret_cast<const ushort_t*>(yrow + nn[nt] * 2));
                        unsafeAtomicAdd(&arow[nn[nt]], wv * yvv);
                    }
                }
            }
        }
    }
}

__global__ __launch_bounds__(256)
void ln_kernel(const float* __restrict__ x, const float* __restrict__ agg,
               const float* __restrict__ g, const float* __restrict__ b,
               float* __restrict__ out0, int N)
{
    int lane = threadIdx.x & 63;
    int row  = blockIdx.x * 4 + (threadIdx.x >> 6);
    if (row >= N) return;
    float4 hx = reinterpret_cast<const float4*>(x)[row * 64 + lane];
    float4 ha = reinterpret_cast<const float4*>(agg)[row * 64 + lane];
    float4 h  = make_float4(hx.x + ha.x, hx.y + ha.y, hx.z + ha.z, hx.w + ha.w);
    float s  = h.x + h.y + h.z + h.w;
    float s2 = h.x * h.x + h.y * h.y + h.z * h.z + h.w * h.w;
    #pragma unroll
    for (int off = 32; off > 0; off >>= 1) {
        s  += __shfl_xor(s,  off, 64);
        s2 += __shfl_xor(s2, off, 64);
    }
    float mu  = s * (1.0f / 256.0f);
    float var = s2 * (1.0f / 256.0f) - mu * mu;
    float inv = rsqrtf(var + F_EPS_LN);
    float4 gv = reinterpret_cast<const float4*>(g)[lane];
    float4 bv = reinterpret_cast<const float4*>(b)[lane];
    float4 o;
    o.x = (h.x - mu) * inv * gv.x + bv.x;
    o.y = (h.y - mu) * inv * gv.y + bv.y;
    o.z = (h.z - mu) * inv * gv.z + bv.z;
    o.w = (h.w - mu) * inv * gv.w + bv.w;
    reinterpret_cast<float4*>(out0)[row * 64 + lane] = o;
}

// ---------------------------------------------------------------------------
extern "C" void kernel_launch(void* const* d_in, const int* in_sizes, int n_in,
                              void* d_out, int out_size, void* d_ws, size_t ws_size,
                              hipStream_t stream)
{
    const float* x       = (const float*)d_in[0];
    const int*   eidx    = (const int*)  d_in[1];
    const float* dist    = (const float*)d_in[2];
    const float* centers = (const float*)d_in[3];
    const float* widths  = (const float*)d_in[4];
    const float* rbf_w1  = (const float*)d_in[5];
    const float* rbf_b1  = (const float*)d_in[6];
    const float* rbf_w2  = (const float*)d_in[7];
    const float* rbf_b2  = (const float*)d_in[8];
    const float* filt_w1 = (const float*)d_in[9];
    const float* filt_b1 = (const float*)d_in[10];
    const float* filt_w2 = (const float*)d_in[11];
    const float* filt_b2 = (const float*)d_in[12];
    const float* filt_w3 = (const float*)d_in[13];
    const float* filt_b3 = (const float*)d_in[14];
    const float* node_w  = (const float*)d_in[15];
    const float* node_b  = (const float*)d_in[16];
    const float* ln_g    = (const float*)d_in[17];
    const float* ln_b    = (const float*)d_in[18];
    const float* gate_w  = (const float*)d_in[19];
    const float* gate_b  = (const float*)d_in[20];

    const int N = in_sizes[0] / 256;
    const int E = in_sizes[2];

    char* wsb = (char*)d_ws;
    size_t off = 0;
    auto alloc = [&](size_t bytes, size_t align) -> char* {
        off = (off + align - 1) & ~(align - 1);
        char* p = wsb + off;
        off += bytes;
        return p;
    };
    ushort_t* y_bf  = (ushort_t*)alloc((size_t)N * 256 * 2, 16);
    ushort_t* wt1   = (ushort_t*)alloc(64 * 64 * 2, 16);
    ushort_t* wcomb = (ushort_t*)alloc(256 * 64 * 2, 16);
    ushort_t* wf2t  = (ushort_t*)alloc(256 * 256 * 2, 16);
    ushort_t* wf3t  = (ushort_t*)alloc(256 * 256 * 2, 16);
    float*    bcomb = (float*)   alloc(256 * 4, 16);
    // optional two-phase region
    int*      cnt   = (int*)     alloc((size_t)N * 4, 16);      // becomes cursor
    int*      start = (int*)     alloc(((size_t)N + 1) * 4, 16);
    int*      slot  = (int*)     alloc((size_t)E * 4, 16);
    int*      colos = (int*)     alloc((size_t)E * 4, 16);
    ushort_t* f1    = (ushort_t*)alloc((size_t)E * 256 * 2, 1024);
    ushort_t* f2    = (ushort_t*)alloc((size_t)E * 256 * 2, 1024);
    ushort_t* Wf    = f1;   // alias: f1 dead after stage B
    const bool two_phase = (off <= ws_size);

    dim3 b256(256);

    // weight prep
    cvt_transpose_kernel<<<dim3((64 * 64 + 255) / 256),   b256, 0, stream>>>(rbf_w1,  wt1, 64, 64, 6);
    combine_w_kernel<<<dim3(64), b256, 0, stream>>>(rbf_w2, filt_w1, wcomb);
    combine_b_kernel<<<dim3(1), b256, 0, stream>>>(rbf_b2, filt_w1, filt_b1, bcomb);
    cvt_transpose_kernel<<<dim3((256 * 256 + 255) / 256), b256, 0, stream>>>(filt_w2, wf2t, 256, 256, 8);
    cvt_transpose_kernel<<<dim3((256 * 256 + 255) / 256), b256, 0, stream>>>(filt_w3, wf3t, 256, 256, 8);

    gemm256_bf16_kernel<<<dim3((N + 63) / 64), b256, 0, stream>>>(x, node_w, node_b, y_bf, N);

    if (two_phase) {
        hipMemsetAsync(cnt, 0, (size_t)N * 4, stream);
        count_kernel<<<dim3((E + 255) / 256), b256, 0, stream>>>(eidx, cnt, E);
        scan_kernel<<<dim3(1), 1024, 0, stream>>>(cnt, start, N);
        scatter_kernel<<<dim3((E + 255) / 256), b256, 0, stream>>>(eidx, cnt, slot, colos, E);

        rbf_f1_kernel<<<dim3((E + 31) / 32), b256, 0, stream>>>(
            dist, centers, widths, wt1, rbf_b1, wcomb, bcomb, f1, E);

        gemm_stage_kernel<0><<<dim3((E + 63) / 64), b256, 0, stream>>>(
            f1, wf2t, filt_b2, f2, nullptr, E);

        gemm_stage_kernel<1><<<dim3((E + 63) / 64), b256, 0, stream>>>(
            f2, wf3t, filt_b3, Wf, slot, E);

        agg_ln2_kernel<<<dim3((N + 3) / 4), b256, 0, stream>>>(
            x, Wf, start, colos, y_bf, ln_g, ln_b, (float*)d_out, N);
    } else {
        hipMemsetAsync(d_out, 0, (size_t)out_size * sizeof(float), stream);
        edge_atomic_kernel<<<dim3((E + 31) / 32), b256, 0, stream>>>(
            dist, eidx, centers, widths,
            wt1, rbf_b1, wcomb, bcomb,
            wf2t, filt_b2, wf3t, filt_b3,
            y_bf, (float*)d_out, E);
        ln_kernel<<<dim3((N + 3) / 4), b256, 0, stream>>>(x, (float*)d_out, ln_g, ln_b, (float*)d_out, N);
    }

    gate_gemm_kernel<<<dim3((N + 63) / 64), b256, 0, stream>>>((float*)d_out, gate_w, gate_b, (float*)d_out, N);
}